// Round 7
// baseline (460.890 us; speedup 1.0000x reference)
//
#include <hip/hip_runtime.h>
#include <cstdint>

using u16 = unsigned short;
using u32 = uint32_t;

__device__ __forceinline__ float bf2f(u16 v) { return __uint_as_float(((u32)v) << 16); }
__device__ __forceinline__ float bflo(u32 u) { return __uint_as_float(u << 16); }
__device__ __forceinline__ float bfhi(u32 u) { return __uint_as_float(u & 0xffff0000u); }
__device__ __forceinline__ u16 f2bf(float f) {
    u32 u = __float_as_uint(f);
    u += 0x7fffu + ((u >> 16) & 1u);   // RNE; exact for bf16-origin values
    return (u16)(u >> 16);
}

// ---- workspace float offsets (R6 layout preserved; WT reuses CWF slot) ----
#define FLAG_OFF 0
#define XF_OFF   16        // 2097152
#define WT_OFF   2097168   // 442368 (transposed conv weights)
#define QWF_OFF  2539536   // 49152
#define AWF_OFF  2588688   // 4096
#define CBF_OFF  2592784   // 192
#define QBF_OFF  2592976   // 192
#define ABF_OFF  2593168   // 64
#define KRW_OFF  2593232   // 504
#define KRH_OFF  2593736   // 504
#define KB_OFF   2594240   // 524288
#define QB_OFF   3118528   // 524288
#define VB_OFF   3642816   // 524288
#define AT_OFF   4167104   // 524288
#define PART_OFF 4691392   // 4 x 1572864  (proven to fit in R6: ~44 MB)

// ---------------------------------------------------------------------------
// Dtype sniffer (verified).
// ---------------------------------------------------------------------------
__global__ void detect_kernel(const u16* __restrict__ x, int* __restrict__ flag) {
    __shared__ int cnt;
    if (threadIdx.x == 0) cnt = 0;
    __syncthreads();
    int c = 0;
    #pragma unroll
    for (int k = 0; k < 16; k++) {
        u16 v = x[threadIdx.x * 16 + k];
        int e = (v >> 7) & 0xFF;
        c += (e >= 110 && e <= 140) ? 1 : 0;
    }
    atomicAdd(&cnt, c);
    __syncthreads();
    if (threadIdx.x == 0) *flag = (cnt > 3300) ? 1 : 0;   // 1 = bf16 inputs
}

// ---------------------------------------------------------------------------
// One launch converts ALL inputs to fp32 (conv_w additionally transposed to
// [p][g=co/8][c][j=co%8] for contiguous streaming in conv_part).
// Segment bounds are the fixed sizes of this problem.
// ---------------------------------------------------------------------------
__global__ __launch_bounds__(256) void cvt_all_kernel(
    const void* __restrict__ x,  const void* __restrict__ cw, const void* __restrict__ cb,
    const void* __restrict__ qw, const void* __restrict__ qb, const void* __restrict__ aw,
    const void* __restrict__ ab, const void* __restrict__ kw_, const void* __restrict__ kh_,
    float* __restrict__ xf, float* __restrict__ wt, float* __restrict__ cbf,
    float* __restrict__ qwf, float* __restrict__ qbf, float* __restrict__ awf,
    float* __restrict__ abf, float* __restrict__ krw, float* __restrict__ krh,
    const int* __restrict__ flag)
{
    const int gid = blockIdx.x * 256 + threadIdx.x;
    const int fl = *flag;
    const void* src; float* dst; int e; int transposed = 0;
    if      (gid < 2097152) { src = x;   dst = xf;  e = gid; }
    else if (gid < 2539520) { src = cw;  dst = wt;  e = gid - 2097152; transposed = 1; }
    else if (gid < 2539712) { src = cb;  dst = cbf; e = gid - 2539520; }
    else if (gid < 2588864) { src = qw;  dst = qwf; e = gid - 2539712; }
    else if (gid < 2589056) { src = qb;  dst = qbf; e = gid - 2588864; }
    else if (gid < 2593152) { src = aw;  dst = awf; e = gid - 2589056; }
    else if (gid < 2593216) { src = ab;  dst = abf; e = gid - 2593152; }
    else if (gid < 2593720) { src = kw_; dst = krw; e = gid - 2593216; }
    else if (gid < 2594224) { src = kh_; dst = krh; e = gid - 2593720; }
    else return;
    const float v = fl ? bf2f(((const u16*)src)[e]) : ((const float*)src)[e];
    int o = e;
    if (transposed) {
        const int k = e / 192, co = e - k * 192;       // k = p*256+c
        const int p = k >> 8, c = k & 255;
        o = ((p * 24 + (co >> 3)) * 256 + c) * 8 + (co & 7);
    }
    dst[o] = v;
}

// ---------------------------------------------------------------------------
// QKV projection (fp32, VERIFIED — unchanged).
// ---------------------------------------------------------------------------
__global__ __launch_bounds__(256) void qkv_kernel(
    const float* __restrict__ xf, const float* __restrict__ wf, const float* __restrict__ bfp,
    float* __restrict__ kbuf, float* __restrict__ qbuf, float* __restrict__ vbuf)
{
    const int third = blockIdx.x, row = blockIdx.y;
    const int b = row >> 5, h = row & 31;
    const int t = threadIdx.x, px = t & 31, cg = t >> 5;
    __shared__ float xs[32 * 257];
    const float* xrow = xf + (size_t)row * 8192;
    #pragma unroll
    for (int k = 0; k < 32; k++) {
        int idx = t + k * 256;
        xs[(idx >> 8) * 257 + (idx & 255)] = xrow[idx];
    }
    __syncthreads();

    const int o0 = third * 64 + cg * 8;
    float acc[8];
    #pragma unroll
    for (int j = 0; j < 8; j++) acc[j] = bfp[o0 + j];

    #pragma unroll 4
    for (int c = 0; c < 256; c++) {
        const float xc = xs[px * 257 + c];
        float4 w0 = *(const float4*)(wf + (size_t)c * 192 + o0);
        float4 w1 = *(const float4*)(wf + (size_t)c * 192 + o0 + 4);
        acc[0] += xc * w0.x; acc[1] += xc * w0.y; acc[2] += xc * w0.z; acc[3] += xc * w0.w;
        acc[4] += xc * w1.x; acc[5] += xc * w1.y; acc[6] += xc * w1.z; acc[7] += xc * w1.w;
    }

    const int i = h * 32 + px;
    float* dst = (third == 0) ? kbuf : (third == 1) ? qbuf : vbuf;
    const float scale = (third == 1) ? 0.35355339059327373f : 1.0f;
    float* op = dst + ((size_t)(b * 8 + cg) * 1024 + i) * 8;
    #pragma unroll
    for (int j = 0; j < 8; j++) op[j] = acc[j] * scale;
}

// ---------------------------------------------------------------------------
// Conv K-split stage 1, v3: grid (3, 128, 4) = 1536 blocks -> 6 blocks/CU.
// Block: 2 output rows x 64 out-ch, one 64-input-ch phase (ks).
// x-tile in LDS as packed bf16 pairs (exact), stride-33 u32 (conflict-free).
// Weights from transposed wt: 64 contiguous bytes per c2-iter, linear stream.
// ---------------------------------------------------------------------------
__global__ __launch_bounds__(256) void conv_part_kernel(
    const float* __restrict__ xf, const float* __restrict__ wt,
    float* __restrict__ part)
{
    const int third = blockIdx.x, rowq = blockIdx.y, ks = blockIdx.z;
    const int b = rowq >> 4, h0 = (rowq & 15) * 2;
    const int t = threadIdx.x, px = t & 31, cg = t >> 5;

    __shared__ u32 xs2[4 * 34 * 33];             // 17952 B

    float acc[2][8];
    #pragma unroll
    for (int r = 0; r < 2; ++r)
        #pragma unroll
        for (int j = 0; j < 8; ++j) acc[r][j] = 0.f;

    // stage rows h0-1 .. h0+2, channels [ks*64, +64) as bf16 pairs
    #pragma unroll
    for (int k = 0; k < 17; ++k) {               // 4*34*32 = 4352 = 17*256
        const int idx = t + k * 256;
        const int row = idx / 1088;
        const int rem = idx - row * 1088;
        const int s = rem >> 5, c2 = rem & 31;
        const int hh = h0 + row - 1, w = s - 1;
        u32 v = 0;
        if (hh >= 0 && hh < 32 && w >= 0 && w < 32) {
            const float* sp = xf + ((size_t)((b * 32 + hh) * 32 + w)) * 256 + ks * 64 + c2 * 2;
            v = (u32)f2bf(sp[0]) | ((u32)f2bf(sp[1]) << 16);
        }
        xs2[(row * 34 + s) * 33 + c2] = v;
    }
    __syncthreads();

    #pragma unroll
    for (int kh = 0; kh < 3; ++kh) {
        #pragma unroll
        for (int kw = 0; kw < 3; ++kw) {
            const int p = kh * 3 + kw;
            const float* wp = wt + ((size_t)(p * 24 + third * 8 + cg) * 256 + ks * 64) * 8;
            const u32* xp0 = xs2 + ((kh + 0) * 34 + px + kw) * 33;
            const u32* xp1 = xs2 + ((kh + 1) * 34 + px + kw) * 33;
            #pragma unroll 4
            for (int c2 = 0; c2 < 32; ++c2) {
                float4 w0 = *(const float4*)(wp + c2 * 16);      // ch even, j0..3
                float4 w1 = *(const float4*)(wp + c2 * 16 + 4);  // ch even, j4..7
                float4 w2 = *(const float4*)(wp + c2 * 16 + 8);  // ch odd,  j0..3
                float4 w3 = *(const float4*)(wp + c2 * 16 + 12); // ch odd,  j4..7
                const u32 v0 = xp0[c2], v1 = xp1[c2];
                const float xl0 = bflo(v0), xh0 = bfhi(v0);
                const float xl1 = bflo(v1), xh1 = bfhi(v1);
                acc[0][0] += xl0 * w0.x; acc[0][1] += xl0 * w0.y; acc[0][2] += xl0 * w0.z; acc[0][3] += xl0 * w0.w;
                acc[0][4] += xl0 * w1.x; acc[0][5] += xl0 * w1.y; acc[0][6] += xl0 * w1.z; acc[0][7] += xl0 * w1.w;
                acc[0][0] += xh0 * w2.x; acc[0][1] += xh0 * w2.y; acc[0][2] += xh0 * w2.z; acc[0][3] += xh0 * w2.w;
                acc[0][4] += xh0 * w3.x; acc[0][5] += xh0 * w3.y; acc[0][6] += xh0 * w3.z; acc[0][7] += xh0 * w3.w;
                acc[1][0] += xl1 * w0.x; acc[1][1] += xl1 * w0.y; acc[1][2] += xl1 * w0.z; acc[1][3] += xl1 * w0.w;
                acc[1][4] += xl1 * w1.x; acc[1][5] += xl1 * w1.y; acc[1][6] += xl1 * w1.z; acc[1][7] += xl1 * w1.w;
                acc[1][0] += xh1 * w2.x; acc[1][1] += xh1 * w2.y; acc[1][2] += xh1 * w2.z; acc[1][3] += xh1 * w2.w;
                acc[1][4] += xh1 * w3.x; acc[1][5] += xh1 * w3.y; acc[1][6] += xh1 * w3.z; acc[1][7] += xh1 * w3.w;
            }
        }
    }

    const int co0 = third * 64 + cg * 8;
    float* pp = part + (size_t)ks * 1572864;
    #pragma unroll
    for (int r = 0; r < 2; ++r) {
        float* op = pp + ((size_t)((b * 32 + h0 + r) * 32) + px) * 192 + co0;
        *(float4*)op       = make_float4(acc[r][0], acc[r][1], acc[r][2], acc[r][3]);
        *(float4*)(op + 4) = make_float4(acc[r][4], acc[r][5], acc[r][6], acc[r][7]);
    }
}

// ---------------------------------------------------------------------------
// Conv K-split stage 2 (VERIFIED — unchanged): sum 4 partials + bias.
// ---------------------------------------------------------------------------
__global__ __launch_bounds__(256) void conv_fin_kernel(
    const float* __restrict__ part, const float* __restrict__ bfp,
    const int* __restrict__ flag, void* __restrict__ out)
{
    const int g = blockIdx.x * 256 + threadIdx.x;   // 0..196607
    const int pix = g / 24, ch0 = (g - pix * 24) * 8;
    const size_t off = (size_t)pix * 192 + ch0;
    float4 a0 = make_float4(bfp[ch0+0], bfp[ch0+1], bfp[ch0+2], bfp[ch0+3]);
    float4 a1 = make_float4(bfp[ch0+4], bfp[ch0+5], bfp[ch0+6], bfp[ch0+7]);
    #pragma unroll
    for (int ks = 0; ks < 4; ++ks) {
        float4 p0 = *(const float4*)(part + (size_t)ks * 1572864 + off);
        float4 p1 = *(const float4*)(part + (size_t)ks * 1572864 + off + 4);
        a0.x += p0.x; a0.y += p0.y; a0.z += p0.z; a0.w += p0.w;
        a1.x += p1.x; a1.y += p1.y; a1.z += p1.z; a1.w += p1.w;
    }
    if (*flag) {
        u16 r8[8] = { f2bf(a0.x), f2bf(a0.y), f2bf(a0.z), f2bf(a0.w),
                      f2bf(a1.x), f2bf(a1.y), f2bf(a1.z), f2bf(a1.w) };
        *(uint4*)((u16*)out + (size_t)pix * 256 + ch0) = *(const uint4*)r8;
    } else {
        float* op = (float*)out + (size_t)pix * 256 + ch0;
        *(float4*)op = a0; *(float4*)(op + 4) = a1;
    }
}

// ---------------------------------------------------------------------------
// Attention (VERIFIED — unchanged).
// ---------------------------------------------------------------------------
__global__ __launch_bounds__(256) void attn_kernel(
    const float* __restrict__ kbuf, const float* __restrict__ qbuf, const float* __restrict__ vbuf,
    const float* __restrict__ krw, const float* __restrict__ krh, float* __restrict__ attnbuf)
{
    const int q4 = blockIdx.x, bn = blockIdx.y;
    const int b = bn >> 3, n = bn & 7;
    const int t = threadIdx.x;
    __shared__ float sK[8192];
    __shared__ float sV[8192];
    {
        const float4* kg = (const float4*)(kbuf + (size_t)bn * 8192);
        const float4* vg = (const float4*)(vbuf + (size_t)bn * 8192);
        float4* sk4 = (float4*)sK; float4* sv4 = (float4*)sV;
        #pragma unroll
        for (int k = 0; k < 8; k++) {
            int idx = t + k * 256;
            sk4[idx] = kg[idx];
            sv4[idx] = vg[idx];
        }
    }
    __syncthreads();

    const int i = q4 * 256 + t;
    const int hq = i >> 5, wq = i & 31;
    float q[8];
    const float* qg = qbuf + ((size_t)bn * 1024 + i) * 8;
    #pragma unroll
    for (int d = 0; d < 8; d++) q[d] = qg[d];

    float rw[32];
    #pragma unroll
    for (int wk = 0; wk < 32; wk++) {
        const float4* kp = (const float4*)(krw + (size_t)(wk - wq + 31) * 8);
        float4 a = kp[0], c = kp[1];
        rw[wk] = q[0]*a.x + q[1]*a.y + q[2]*a.z + q[3]*a.w
               + q[4]*c.x + q[5]*c.y + q[6]*c.z + q[7]*c.w;
    }

    float l = 0.f;
    float vacc[8] = {0.f,0.f,0.f,0.f,0.f,0.f,0.f,0.f};
    for (int hk = 0; hk < 32; hk++) {
        const float4* hp = (const float4*)(krh + (size_t)(hk - hq + 31) * 8);
        float4 a = hp[0], c = hp[1];
        const float rh = q[0]*a.x + q[1]*a.y + q[2]*a.z + q[3]*a.w
                       + q[4]*c.x + q[5]*c.y + q[6]*c.z + q[7]*c.w;
        const float4* kr = (const float4*)sK + hk * 64;
        const float4* vr = (const float4*)sV + hk * 64;
        #pragma unroll
        for (int wk = 0; wk < 32; wk++) {
            float4 k0 = kr[2*wk], k1 = kr[2*wk+1];
            float s = q[0]*k0.x + q[1]*k0.y + q[2]*k0.z + q[3]*k0.w
                    + q[4]*k1.x + q[5]*k1.y + q[6]*k1.z + q[7]*k1.w + rw[wk] + rh;
            s = fminf(s, 60.0f);
            float p = __expf(s);
            l += p;
            float4 v0 = vr[2*wk], v1 = vr[2*wk+1];
            vacc[0] += p*v0.x; vacc[1] += p*v0.y; vacc[2] += p*v0.z; vacc[3] += p*v0.w;
            vacc[4] += p*v1.x; vacc[5] += p*v1.y; vacc[6] += p*v1.z; vacc[7] += p*v1.w;
        }
    }

    const float inv = 1.0f / fmaxf(l, 1e-30f);
    float* op = attnbuf + ((size_t)b * 1024 + i) * 64 + n * 8;
    #pragma unroll
    for (int d = 0; d < 8; d++) op[d] = vacc[d] * inv;
}

__global__ __launch_bounds__(256) void proj_kernel(
    const float* __restrict__ attnbuf, const float* __restrict__ awf, const float* __restrict__ abf,
    const int* __restrict__ flag, void* __restrict__ out)
{
    const int g = blockIdx.x * 256 + threadIdx.x;
    const int px = g >> 6, o = g & 63;
    const float* ar = attnbuf + (size_t)px * 64;
    float acc = abf[o];
    #pragma unroll 8
    for (int c = 0; c < 64; c++) acc += ar[c] * awf[c * 64 + o];
    if (*flag) ((u16*)out)[(size_t)px * 256 + 192 + o] = f2bf(acc);
    else       ((float*)out)[(size_t)px * 256 + 192 + o] = acc;
}

// ---------------------------------------------------------------------------
extern "C" void kernel_launch(void* const* d_in, const int* in_sizes, int n_in,
                              void* d_out, int out_size, void* d_ws, size_t ws_size,
                              hipStream_t stream)
{
    float* ws = (float*)d_ws;
    int*   flag = (int*)(ws + FLAG_OFF);
    float* xf   = ws + XF_OFF;
    float* wt   = ws + WT_OFF;
    float* qwf  = ws + QWF_OFF;
    float* awf  = ws + AWF_OFF;
    float* cbf  = ws + CBF_OFF;
    float* qbf  = ws + QBF_OFF;
    float* abf  = ws + ABF_OFF;
    float* krw  = ws + KRW_OFF;
    float* krh  = ws + KRH_OFF;
    float* kbuf = ws + KB_OFF;
    float* qbuf = ws + QB_OFF;
    float* vbuf = ws + VB_OFF;
    float* atb  = ws + AT_OFF;
    float* part = ws + PART_OFF;

    detect_kernel<<<1, 256, 0, stream>>>((const u16*)d_in[0], flag);

    cvt_all_kernel<<<10134, 256, 0, stream>>>(
        d_in[0], d_in[1], d_in[2], d_in[3], d_in[4], d_in[5], d_in[6], d_in[7], d_in[8],
        xf, wt, cbf, qwf, qbf, awf, abf, krw, krh, flag);

    qkv_kernel      <<<dim3(3, 256),    256, 0, stream>>>(xf, qwf, qbf, kbuf, qbuf, vbuf);
    conv_part_kernel<<<dim3(3, 128, 4), 256, 0, stream>>>(xf, wt, part);
    conv_fin_kernel <<<768,             256, 0, stream>>>(part, cbf, flag, d_out);
    attn_kernel     <<<dim3(4, 64),     256, 0, stream>>>(kbuf, qbuf, vbuf, krw, krh, atb);
    proj_kernel     <<<2048,            256, 0, stream>>>(atb, awf, abf, flag, d_out);
}

// Round 8
// 448.437 us; speedup vs baseline: 1.0278x; 1.0278x over previous
//
#include <hip/hip_runtime.h>
#include <cstdint>

using u16 = unsigned short;
using u32 = uint32_t;

typedef __attribute__((ext_vector_type(8))) short bf16x8;   // 8 bf16 = 4 VGPRs
typedef __attribute__((ext_vector_type(4))) float f32x4;    // MFMA accumulator

__device__ __forceinline__ float bf2f(u16 v) { return __uint_as_float(((u32)v) << 16); }
__device__ __forceinline__ u16 f2bf(float f) {
    u32 u = __float_as_uint(f);
    u += 0x7fffu + ((u >> 16) & 1u);   // RNE
    return (u16)(u >> 16);
}

// ---- workspace float offsets (R6/R7 layout preserved) ----
#define FLAG_OFF 0
#define XF_OFF   16        // 2097152
#define WSH_OFF  2097168   // conv weight bf16 fragments: u16[442368] = 221184 f
#define QWF_OFF  2539536   // 49152
#define AWF_OFF  2588688   // 4096
#define CBF_OFF  2592784   // 192
#define QBF_OFF  2592976   // 192
#define ABF_OFF  2593168   // 64
#define KRW_OFF  2593232   // 504
#define KRH_OFF  2593736   // 504
#define KB_OFF   2594240   // 524288
#define QB_OFF   3118528   // 524288
#define VB_OFF   3642816   // 524288
#define AT_OFF   4167104   // 524288
#define LP_OFF   4691392   // attn l partials: 4*64*1024 = 262144
#define VP_OFF   4953536   // attn v partials: 2097152 (region proven to fit in R6)

// ---------------------------------------------------------------------------
// Dtype sniffer (verified; returns 0 on this problem's fp32 inputs).
// ---------------------------------------------------------------------------
__global__ void detect_kernel(const u16* __restrict__ x, int* __restrict__ flag) {
    __shared__ int cnt;
    if (threadIdx.x == 0) cnt = 0;
    __syncthreads();
    int c = 0;
    #pragma unroll
    for (int k = 0; k < 16; k++) {
        u16 v = x[threadIdx.x * 16 + k];
        int e = (v >> 7) & 0xFF;
        c += (e >= 110 && e <= 140) ? 1 : 0;
    }
    atomicAdd(&cnt, c);
    __syncthreads();
    if (threadIdx.x == 0) *flag = (cnt > 3300) ? 1 : 0;   // 1 = bf16 inputs
}

// ---------------------------------------------------------------------------
// One launch normalizes all non-conv-w inputs to fp32 (exact either mode).
// ---------------------------------------------------------------------------
__global__ __launch_bounds__(256) void cvt_all_kernel(
    const void* __restrict__ x,  const void* __restrict__ cb, const void* __restrict__ qw,
    const void* __restrict__ qb, const void* __restrict__ aw, const void* __restrict__ ab,
    const void* __restrict__ kw_, const void* __restrict__ kh_,
    float* __restrict__ xf, float* __restrict__ cbf, float* __restrict__ qwf,
    float* __restrict__ qbf, float* __restrict__ awf, float* __restrict__ abf,
    float* __restrict__ krw, float* __restrict__ krh, const int* __restrict__ flag)
{
    const int gid = blockIdx.x * 256 + threadIdx.x;
    const void* src; float* dst; int e;
    if      (gid < 2097152) { src = x;   dst = xf;  e = gid; }
    else if (gid < 2097344) { src = cb;  dst = cbf; e = gid - 2097152; }
    else if (gid < 2146496) { src = qw;  dst = qwf; e = gid - 2097344; }
    else if (gid < 2146688) { src = qb;  dst = qbf; e = gid - 2146496; }
    else if (gid < 2150784) { src = aw;  dst = awf; e = gid - 2146688; }
    else if (gid < 2150848) { src = ab;  dst = abf; e = gid - 2150784; }
    else if (gid < 2151352) { src = kw_; dst = krw; e = gid - 2150848; }
    else if (gid < 2151856) { src = kh_; dst = krh; e = gid - 2151352; }
    else return;
    dst[e] = (*flag) ? bf2f(((const u16*)src)[e]) : ((const float*)src)[e];
}

// ---------------------------------------------------------------------------
// Conv-weight shuffle into MFMA B-fragment order, FLAG-ADAPTIVE source reads
// (the R3/R4 NaN root cause: conv_w is fp32, was read as u16).
// Fragment g=(kk*12+tile)*64+lane, elem j -> B[k=kk*32+(lane>>4)*8+j][n=tile*16+(lane&15)]
// ---------------------------------------------------------------------------
__global__ __launch_bounds__(256) void wshufC_kernel(
    const void* __restrict__ w, u16* __restrict__ o, const int* __restrict__ flag)
{
    const int g = blockIdx.x * 256 + threadIdx.x;          // 0..55295
    const int kk = g / 768, rem = g % 768;
    const int tile = rem >> 6, lane = rem & 63;
    const int n = tile * 16 + (lane & 15);
    const int fl = *flag;
    u16 tmp[8];
    #pragma unroll
    for (int j = 0; j < 8; j++) {
        const size_t k = (size_t)(kk * 32 + ((lane >> 4) << 3) + j);   // 0..2303
        tmp[j] = fl ? ((const u16*)w)[k * 192 + n]
                    : f2bf(((const float*)w)[k * 192 + n]);
    }
    *(uint4*)(o + (size_t)g * 8) = *(const uint4*)tmp;
}

// ---------------------------------------------------------------------------
// QKV projection (fp32, VERIFIED — unchanged).
// ---------------------------------------------------------------------------
__global__ __launch_bounds__(256) void qkv_kernel(
    const float* __restrict__ xf, const float* __restrict__ wf, const float* __restrict__ bfp,
    float* __restrict__ kbuf, float* __restrict__ qbuf, float* __restrict__ vbuf)
{
    const int third = blockIdx.x, row = blockIdx.y;
    const int b = row >> 5, h = row & 31;
    const int t = threadIdx.x, px = t & 31, cg = t >> 5;
    __shared__ float xs[32 * 257];
    const float* xrow = xf + (size_t)row * 8192;
    #pragma unroll
    for (int k = 0; k < 32; k++) {
        int idx = t + k * 256;
        xs[(idx >> 8) * 257 + (idx & 255)] = xrow[idx];
    }
    __syncthreads();

    const int o0 = third * 64 + cg * 8;
    float acc[8];
    #pragma unroll
    for (int j = 0; j < 8; j++) acc[j] = bfp[o0 + j];

    #pragma unroll 4
    for (int c = 0; c < 256; c++) {
        const float xc = xs[px * 257 + c];
        float4 w0 = *(const float4*)(wf + (size_t)c * 192 + o0);
        float4 w1 = *(const float4*)(wf + (size_t)c * 192 + o0 + 4);
        acc[0] += xc * w0.x; acc[1] += xc * w0.y; acc[2] += xc * w0.z; acc[3] += xc * w0.w;
        acc[4] += xc * w1.x; acc[5] += xc * w1.y; acc[6] += xc * w1.z; acc[7] += xc * w1.w;
    }

    const int i = h * 32 + px;
    float* dst = (third == 0) ? kbuf : (third == 1) ? qbuf : vbuf;
    const float scale = (third == 1) ? 0.35355339059327373f : 1.0f;
    float* op = dst + ((size_t)(b * 8 + cg) * 1024 + i) * 8;
    #pragma unroll
    for (int j = 0; j < 8; j++) op[j] = acc[j] * scale;
}

// ---------------------------------------------------------------------------
// Conv 3x3 SAME 256->192 implicit GEMM, bf16 MFMA 16x16x32 (R4 body, audited;
// fixed: bias from fp32 cbf, flag-adaptive output store).
// grid (2, 256): cout half x (b*32+h). 4 waves: Mtile=wave&1, 3 N-tiles each.
// ---------------------------------------------------------------------------
__global__ __launch_bounds__(256) void conv_mfma_kernel(
    const float* __restrict__ xf, const u16* __restrict__ wsh, const float* __restrict__ cbf,
    const int* __restrict__ flag, void* __restrict__ out)
{
    const int coh = blockIdx.x, row = blockIdx.y;
    const int b = row >> 5, h = row & 31;
    const int t = threadIdx.x;
    __shared__ u16 xs[3 * 34 * 264];                        // 53856 B

    #pragma unroll
    for (int r = 0; r < 3; ++r) {
        const int hh = h + r - 1;
        if (t < 64) {                                       // zero border cols s=0, s=33
            const int s = (t >> 5) ? 33 : 0, cq = t & 31;
            *(uint4*)(xs + (r * 34 + s) * 264 + cq * 8) = make_uint4(0, 0, 0, 0);
        }
        const bool ok = (hh >= 0) && (hh < 32);
        const float* src = xf + ((size_t)((b * 32 + (ok ? hh : 0)) * 32)) * 256;
        #pragma unroll
        for (int i = 0; i < 8; ++i) {
            const int idx = t + i * 256;                    // 0..2047
            const int px = idx >> 6, c4 = idx & 63;
            float4 v = ok ? *(const float4*)(src + px * 256 + c4 * 4)
                          : make_float4(0.f, 0.f, 0.f, 0.f);
            u32 lo = (u32)f2bf(v.x) | ((u32)f2bf(v.y) << 16);
            u32 hi = (u32)f2bf(v.z) | ((u32)f2bf(v.w) << 16);
            *(uint2*)(xs + (r * 34 + 1 + px) * 264 + c4 * 4) = make_uint2(lo, hi);
        }
    }
    __syncthreads();

    const int lane = t & 63, wave = t >> 6;
    const int Mtile = wave & 1;
    const int tg0 = coh * 6 + (wave >> 1) * 3;
    const int l15 = lane & 15, quad = lane >> 4;

    f32x4 acc[3] = {{0,0,0,0},{0,0,0,0},{0,0,0,0}};

    #pragma unroll
    for (int p = 0; p < 9; ++p) {
        const int kh = p / 3, kw = p - kh * 3;
        const u16* ap = xs + (kh * 34 + kw + Mtile * 16 + l15) * 264 + quad * 8;
        #pragma unroll
        for (int ck = 0; ck < 8; ++ck) {
            const int kk = p * 8 + ck;
            const bf16x8 av = *(const bf16x8*)(ap + ck * 32);
            const u16* wp = wsh + ((size_t)(kk * 12 + tg0) * 64 + lane) * 8;
            const bf16x8 b0 = *(const bf16x8*)(wp);
            const bf16x8 b1 = *(const bf16x8*)(wp + 512);
            const bf16x8 b2 = *(const bf16x8*)(wp + 1024);
            acc[0] = __builtin_amdgcn_mfma_f32_16x16x32_bf16(av, b0, acc[0], 0, 0, 0);
            acc[1] = __builtin_amdgcn_mfma_f32_16x16x32_bf16(av, b1, acc[1], 0, 0, 0);
            acc[2] = __builtin_amdgcn_mfma_f32_16x16x32_bf16(av, b2, acc[2], 0, 0, 0);
        }
    }

    // D layout (m89-verified): col = lane&15, row = quad*4 + reg
    const int px0 = Mtile * 16 + quad * 4;
    const int fl = *flag;
    #pragma unroll
    for (int ti = 0; ti < 3; ++ti) {
        const int co = (tg0 + ti) * 16 + l15;
        const float bias = cbf[co];
        #pragma unroll
        for (int r = 0; r < 4; ++r) {
            const size_t oidx = ((size_t)row * 32 + px0 + r) * 256 + co;
            const float v = acc[ti][r] + bias;
            if (fl) ((u16*)out)[oidx] = f2bf(v);
            else    ((float*)out)[oidx] = v;
        }
    }
}

// ---------------------------------------------------------------------------
// Attention stage 1: 4-way KEY split of the verified kernel. grid (4,64,4)
// = 1024 blocks, 16 KB LDS. Partial l and unnormalized vacc to workspace.
// ---------------------------------------------------------------------------
__global__ __launch_bounds__(256) void attn_part_kernel(
    const float* __restrict__ kbuf, const float* __restrict__ qbuf, const float* __restrict__ vbuf,
    const float* __restrict__ krw, const float* __restrict__ krh,
    float* __restrict__ lpart, float* __restrict__ vpart)
{
    const int q4 = blockIdx.x, bn = blockIdx.y, ksp = blockIdx.z;
    const int t = threadIdx.x;
    __shared__ float sK[2048];
    __shared__ float sV[2048];
    {
        const float4* kg = (const float4*)(kbuf + (size_t)bn * 8192 + ksp * 2048);
        const float4* vg = (const float4*)(vbuf + (size_t)bn * 8192 + ksp * 2048);
        float4* sk4 = (float4*)sK; float4* sv4 = (float4*)sV;
        #pragma unroll
        for (int k = 0; k < 2; k++) {
            int idx = t + k * 256;                           // 0..511 float4s
            sk4[idx] = kg[idx];
            sv4[idx] = vg[idx];
        }
    }
    __syncthreads();

    const int i = q4 * 256 + t;
    const int hq = i >> 5, wq = i & 31;
    float q[8];
    const float* qg = qbuf + ((size_t)bn * 1024 + i) * 8;
    #pragma unroll
    for (int d = 0; d < 8; d++) q[d] = qg[d];

    float rw[32];
    #pragma unroll
    for (int wk = 0; wk < 32; wk++) {
        const float4* kp = (const float4*)(krw + (size_t)(wk - wq + 31) * 8);
        float4 a = kp[0], c = kp[1];
        rw[wk] = q[0]*a.x + q[1]*a.y + q[2]*a.z + q[3]*a.w
               + q[4]*c.x + q[5]*c.y + q[6]*c.z + q[7]*c.w;
    }

    float l = 0.f;
    float vacc[8] = {0.f,0.f,0.f,0.f,0.f,0.f,0.f,0.f};
    #pragma unroll
    for (int hk8 = 0; hk8 < 8; hk8++) {
        const int hk = ksp * 8 + hk8;
        const float4* hp = (const float4*)(krh + (size_t)(hk - hq + 31) * 8);
        float4 a = hp[0], c = hp[1];
        const float rh = q[0]*a.x + q[1]*a.y + q[2]*a.z + q[3]*a.w
                       + q[4]*c.x + q[5]*c.y + q[6]*c.z + q[7]*c.w;
        const float4* kr = (const float4*)sK + hk8 * 64;
        const float4* vr = (const float4*)sV + hk8 * 64;
        #pragma unroll
        for (int wk = 0; wk < 32; wk++) {
            float4 k0 = kr[2*wk], k1 = kr[2*wk+1];
            float s = q[0]*k0.x + q[1]*k0.y + q[2]*k0.z + q[3]*k0.w
                    + q[4]*k1.x + q[5]*k1.y + q[6]*k1.z + q[7]*k1.w + rw[wk] + rh;
            s = fminf(s, 60.0f);                 // exact for correct data
            float p = __expf(s);
            l += p;
            float4 v0 = vr[2*wk], v1 = vr[2*wk+1];
            vacc[0] += p*v0.x; vacc[1] += p*v0.y; vacc[2] += p*v0.z; vacc[3] += p*v0.w;
            vacc[4] += p*v1.x; vacc[5] += p*v1.y; vacc[6] += p*v1.z; vacc[7] += p*v1.w;
        }
    }

    const size_t slot = ((size_t)ksp * 64 + bn) * 1024 + i;
    lpart[slot] = l;
    float* vp = vpart + slot * 8;
    #pragma unroll
    for (int d = 0; d < 8; d++) vp[d] = vacc[d];
}

// ---------------------------------------------------------------------------
// Attention stage 2: merge 4 key-split partials (plain sums), normalize.
// ---------------------------------------------------------------------------
__global__ __launch_bounds__(256) void attn_fin_kernel(
    const float* __restrict__ lpart, const float* __restrict__ vpart,
    float* __restrict__ attnbuf)
{
    const int g = blockIdx.x * 256 + threadIdx.x;   // 0..524287
    const int bn = g >> 13, rem = g & 8191;
    const int i = rem >> 3, d = rem & 7;
    float l = 0.f, v = 0.f;
    #pragma unroll
    for (int ks = 0; ks < 4; ks++) {
        const size_t slot = ((size_t)ks * 64 + bn) * 1024 + i;
        l += lpart[slot];
        v += vpart[slot * 8 + d];
    }
    const int b = bn >> 3, n = bn & 7;
    attnbuf[((size_t)b * 1024 + i) * 64 + n * 8 + d] = v / fmaxf(l, 1e-30f);
}

// ---------------------------------------------------------------------------
// Output projection (VERIFIED — unchanged).
// ---------------------------------------------------------------------------
__global__ __launch_bounds__(256) void proj_kernel(
    const float* __restrict__ attnbuf, const float* __restrict__ awf, const float* __restrict__ abf,
    const int* __restrict__ flag, void* __restrict__ out)
{
    const int g = blockIdx.x * 256 + threadIdx.x;
    const int px = g >> 6, o = g & 63;
    const float* ar = attnbuf + (size_t)px * 64;
    float acc = abf[o];
    #pragma unroll 8
    for (int c = 0; c < 64; c++) acc += ar[c] * awf[c * 64 + o];
    if (*flag) ((u16*)out)[(size_t)px * 256 + 192 + o] = f2bf(acc);
    else       ((float*)out)[(size_t)px * 256 + 192 + o] = acc;
}

// ---------------------------------------------------------------------------
extern "C" void kernel_launch(void* const* d_in, const int* in_sizes, int n_in,
                              void* d_out, int out_size, void* d_ws, size_t ws_size,
                              hipStream_t stream)
{
    float* ws = (float*)d_ws;
    int*   flag = (int*)(ws + FLAG_OFF);
    float* xf   = ws + XF_OFF;
    u16*   wsh  = (u16*)(ws + WSH_OFF);
    float* qwf  = ws + QWF_OFF;
    float* awf  = ws + AWF_OFF;
    float* cbf  = ws + CBF_OFF;
    float* qbf  = ws + QBF_OFF;
    float* abf  = ws + ABF_OFF;
    float* krw  = ws + KRW_OFF;
    float* krh  = ws + KRH_OFF;
    float* kbuf = ws + KB_OFF;
    float* qbuf = ws + QB_OFF;
    float* vbuf = ws + VB_OFF;
    float* atb  = ws + AT_OFF;
    float* lpart = ws + LP_OFF;
    float* vpart = ws + VP_OFF;

    detect_kernel<<<1, 256, 0, stream>>>((const u16*)d_in[0], flag);

    cvt_all_kernel<<<8406, 256, 0, stream>>>(
        d_in[0], d_in[2], d_in[3], d_in[4], d_in[5], d_in[6], d_in[7], d_in[8],
        xf, cbf, qwf, qbf, awf, abf, krw, krh, flag);
    wshufC_kernel<<<216, 256, 0, stream>>>(d_in[1], wsh, flag);

    qkv_kernel      <<<dim3(3, 256),   256, 0, stream>>>(xf, qwf, qbf, kbuf, qbuf, vbuf);
    conv_mfma_kernel<<<dim3(2, 256),   256, 0, stream>>>(xf, wsh, cbf, flag, d_out);
    attn_part_kernel<<<dim3(4, 64, 4), 256, 0, stream>>>(kbuf, qbuf, vbuf, krw, krh, lpart, vpart);
    attn_fin_kernel <<<2048,           256, 0, stream>>>(lpart, vpart, atb);
    proj_kernel     <<<2048,           256, 0, stream>>>(atb, awf, abf, flag, d_out);
}

// Round 9
// 222.892 us; speedup vs baseline: 2.0678x; 2.0119x over previous
//
#include <hip/hip_runtime.h>
#include <cstdint>

using u16 = unsigned short;
using u32 = uint32_t;

typedef __attribute__((ext_vector_type(8))) short bf16x8;   // 8 bf16 = 4 VGPRs
typedef __attribute__((ext_vector_type(4))) float f32x4;    // MFMA accumulator

__device__ __forceinline__ float bf2f(u16 v) { return __uint_as_float(((u32)v) << 16); }
__device__ __forceinline__ u16 f2bf(float f) {
    u32 u = __float_as_uint(f);
    u += 0x7fffu + ((u >> 16) & 1u);   // RNE
    return (u16)(u >> 16);
}

// ---- workspace float offsets ----
#define FLAG_OFF 0
#define XF_OFF   16        // 2097152
#define WSH_OFF  2097168   // conv weight bf16 fragments: u16[442368] = 221184 f
#define QWF_OFF  2539536   // 49152 (still written by cvt_all; unused now)
#define AWF_OFF  2588688   // 4096
#define CBF_OFF  2592784   // 192
#define QBF_OFF  2592976   // 192
#define ABF_OFF  2593168   // 64
#define KRW_OFF  2593232   // 504
#define KRH_OFF  2593736   // 504
#define KB_OFF   2594240   // 524288
#define QB_OFF   3118528   // 524288
#define VB_OFF   3642816   // 524288
#define AT_OFF   4167104   // 524288
#define LP_OFF   4691392   // attn l partials: 262144
#define VP_OFF   4953536   // attn v partials: 2097152
#define WSHQ_OFF 7050688   // qkv weight bf16 fragments: u16[49152] = 24576 f
                           // end 7075264 floats ~ 28.3 MB (44 MB proven in R6)

// ---------------------------------------------------------------------------
// Dtype sniffer (verified; returns 0 on this problem's fp32 inputs).
// ---------------------------------------------------------------------------
__global__ void detect_kernel(const u16* __restrict__ x, int* __restrict__ flag) {
    __shared__ int cnt;
    if (threadIdx.x == 0) cnt = 0;
    __syncthreads();
    int c = 0;
    #pragma unroll
    for (int k = 0; k < 16; k++) {
        u16 v = x[threadIdx.x * 16 + k];
        int e = (v >> 7) & 0xFF;
        c += (e >= 110 && e <= 140) ? 1 : 0;
    }
    atomicAdd(&cnt, c);
    __syncthreads();
    if (threadIdx.x == 0) *flag = (cnt > 3300) ? 1 : 0;   // 1 = bf16 inputs
}

// ---------------------------------------------------------------------------
// One launch normalizes inputs to fp32 (exact either mode). VERIFIED.
// ---------------------------------------------------------------------------
__global__ __launch_bounds__(256) void cvt_all_kernel(
    const void* __restrict__ x,  const void* __restrict__ cb, const void* __restrict__ qw,
    const void* __restrict__ qb, const void* __restrict__ aw, const void* __restrict__ ab,
    const void* __restrict__ kw_, const void* __restrict__ kh_,
    float* __restrict__ xf, float* __restrict__ cbf, float* __restrict__ qwf,
    float* __restrict__ qbf, float* __restrict__ awf, float* __restrict__ abf,
    float* __restrict__ krw, float* __restrict__ krh, const int* __restrict__ flag)
{
    const int gid = blockIdx.x * 256 + threadIdx.x;
    const void* src; float* dst; int e;
    if      (gid < 2097152) { src = x;   dst = xf;  e = gid; }
    else if (gid < 2097344) { src = cb;  dst = cbf; e = gid - 2097152; }
    else if (gid < 2146496) { src = qw;  dst = qwf; e = gid - 2097344; }
    else if (gid < 2146688) { src = qb;  dst = qbf; e = gid - 2146496; }
    else if (gid < 2150784) { src = aw;  dst = awf; e = gid - 2146688; }
    else if (gid < 2150848) { src = ab;  dst = abf; e = gid - 2150784; }
    else if (gid < 2151352) { src = kw_; dst = krw; e = gid - 2150848; }
    else if (gid < 2151856) { src = kh_; dst = krh; e = gid - 2151352; }
    else return;
    dst[e] = (*flag) ? bf2f(((const u16*)src)[e]) : ((const float*)src)[e];
}

// ---------------------------------------------------------------------------
// Weight shuffles into MFMA B-fragment order, flag-adaptive reads. VERIFIED
// (conv variant, R8). Fragment g=(kk*12+tile)*64+lane, elem j ->
// B[k=kk*32+(lane>>4)*8+j][n=tile*16+(lane&15)], B[k][n]=w[k*192+n].
// ---------------------------------------------------------------------------
__global__ __launch_bounds__(256) void wshufC_kernel(
    const void* __restrict__ w, u16* __restrict__ o, const int* __restrict__ flag)
{
    const int g = blockIdx.x * 256 + threadIdx.x;          // 0..55295
    const int kk = g / 768, rem = g % 768;
    const int tile = rem >> 6, lane = rem & 63;
    const int n = tile * 16 + (lane & 15);
    const int fl = *flag;
    u16 tmp[8];
    #pragma unroll
    for (int j = 0; j < 8; j++) {
        const size_t k = (size_t)(kk * 32 + ((lane >> 4) << 3) + j);   // 0..2303
        tmp[j] = fl ? ((const u16*)w)[k * 192 + n]
                    : f2bf(((const float*)w)[k * 192 + n]);
    }
    *(uint4*)(o + (size_t)g * 8) = *(const uint4*)tmp;
}

__global__ __launch_bounds__(256) void wshufQ_kernel(
    const void* __restrict__ w, u16* __restrict__ o, const int* __restrict__ flag)
{
    const int g = blockIdx.x * 256 + threadIdx.x;          // 0..6143
    const int kk = g / 768, rem = g % 768;
    const int tile = rem >> 6, lane = rem & 63;
    const int n = tile * 16 + (lane & 15);
    const int fl = *flag;
    u16 tmp[8];
    #pragma unroll
    for (int j = 0; j < 8; j++) {
        const size_t k = (size_t)(kk * 32 + ((lane >> 4) << 3) + j);   // 0..255
        tmp[j] = fl ? ((const u16*)w)[k * 192 + n]
                    : f2bf(((const float*)w)[k * 192 + n]);
    }
    *(uint4*)(o + (size_t)g * 8) = *(const uint4*)tmp;
}

// ---------------------------------------------------------------------------
// QKV as implicit GEMM (M=8192,N=192,K=256), bf16 MFMA — same machinery as
// the R8-verified conv kernel; R3-audited k/q/v-split epilogue.
// ---------------------------------------------------------------------------
__global__ __launch_bounds__(256) void qkv_mfma_kernel(
    const float* __restrict__ xf, const u16* __restrict__ wsh, const float* __restrict__ qbf,
    float* __restrict__ kbuf, float* __restrict__ qbuf, float* __restrict__ vbuf)
{
    const int coh = blockIdx.x, row = blockIdx.y;
    const int b = row >> 5, h = row & 31;
    const int t = threadIdx.x;
    __shared__ u16 xs[32 * 264];                            // 16896 B

    const float* src = xf + (size_t)row * 8192;
    #pragma unroll
    for (int i = 0; i < 8; ++i) {
        const int idx = t + i * 256;                        // 0..2047
        const int px = idx >> 6, c4 = idx & 63;
        float4 v = *(const float4*)(src + px * 256 + c4 * 4);
        u32 lo = (u32)f2bf(v.x) | ((u32)f2bf(v.y) << 16);
        u32 hi = (u32)f2bf(v.z) | ((u32)f2bf(v.w) << 16);
        *(uint2*)(xs + px * 264 + c4 * 4) = make_uint2(lo, hi);
    }
    __syncthreads();

    const int lane = t & 63, wave = t >> 6;
    const int Mtile = wave & 1;
    const int tg0 = coh * 6 + (wave >> 1) * 3;
    const int l15 = lane & 15, quad = lane >> 4;

    f32x4 acc[3] = {{0,0,0,0},{0,0,0,0},{0,0,0,0}};

    const u16* ap = xs + (Mtile * 16 + l15) * 264 + quad * 8;
    #pragma unroll
    for (int kk = 0; kk < 8; ++kk) {
        const bf16x8 av = *(const bf16x8*)(ap + kk * 32);
        const u16* wp = wsh + ((size_t)(kk * 12 + tg0) * 64 + lane) * 8;
        const bf16x8 b0 = *(const bf16x8*)(wp);
        const bf16x8 b1 = *(const bf16x8*)(wp + 512);
        const bf16x8 b2 = *(const bf16x8*)(wp + 1024);
        acc[0] = __builtin_amdgcn_mfma_f32_16x16x32_bf16(av, b0, acc[0], 0, 0, 0);
        acc[1] = __builtin_amdgcn_mfma_f32_16x16x32_bf16(av, b1, acc[1], 0, 0, 0);
        acc[2] = __builtin_amdgcn_mfma_f32_16x16x32_bf16(av, b2, acc[2], 0, 0, 0);
    }

    // D layout (verified): col = lane&15, row = quad*4 + reg
    const int px0 = Mtile * 16 + quad * 4;
    #pragma unroll
    for (int ti = 0; ti < 3; ++ti) {
        const int tg = tg0 + ti;                            // 0..11
        const int o = tg * 16 + l15;                        // 0..191
        const int third = tg >> 2;                          // 0=k,1=q,2=v
        const int within = o - third * 64;
        const int n = within >> 3, d = within & 7;
        const float bias = qbf[o];
        const float scale = (third == 1) ? 0.35355339059327373f : 1.0f;
        float* dst = (third == 0) ? kbuf : (third == 1) ? qbuf : vbuf;
        #pragma unroll
        for (int r = 0; r < 4; ++r) {
            const int i = h * 32 + px0 + r;
            dst[((size_t)(b * 8 + n) * 1024 + i) * 8 + d] = (acc[ti][r] + bias) * scale;
        }
    }
}

// ---------------------------------------------------------------------------
// Conv 3x3 SAME 256->192 implicit GEMM, bf16 MFMA. VERIFIED R8 — unchanged.
// ---------------------------------------------------------------------------
__global__ __launch_bounds__(256) void conv_mfma_kernel(
    const float* __restrict__ xf, const u16* __restrict__ wsh, const float* __restrict__ cbf,
    const int* __restrict__ flag, void* __restrict__ out)
{
    const int coh = blockIdx.x, row = blockIdx.y;
    const int b = row >> 5, h = row & 31;
    const int t = threadIdx.x;
    __shared__ u16 xs[3 * 34 * 264];                        // 53856 B

    #pragma unroll
    for (int r = 0; r < 3; ++r) {
        const int hh = h + r - 1;
        if (t < 64) {
            const int s = (t >> 5) ? 33 : 0, cq = t & 31;
            *(uint4*)(xs + (r * 34 + s) * 264 + cq * 8) = make_uint4(0, 0, 0, 0);
        }
        const bool ok = (hh >= 0) && (hh < 32);
        const float* src = xf + ((size_t)((b * 32 + (ok ? hh : 0)) * 32)) * 256;
        #pragma unroll
        for (int i = 0; i < 8; ++i) {
            const int idx = t + i * 256;
            const int px = idx >> 6, c4 = idx & 63;
            float4 v = ok ? *(const float4*)(src + px * 256 + c4 * 4)
                          : make_float4(0.f, 0.f, 0.f, 0.f);
            u32 lo = (u32)f2bf(v.x) | ((u32)f2bf(v.y) << 16);
            u32 hi = (u32)f2bf(v.z) | ((u32)f2bf(v.w) << 16);
            *(uint2*)(xs + (r * 34 + 1 + px) * 264 + c4 * 4) = make_uint2(lo, hi);
        }
    }
    __syncthreads();

    const int lane = t & 63, wave = t >> 6;
    const int Mtile = wave & 1;
    const int tg0 = coh * 6 + (wave >> 1) * 3;
    const int l15 = lane & 15, quad = lane >> 4;

    f32x4 acc[3] = {{0,0,0,0},{0,0,0,0},{0,0,0,0}};

    #pragma unroll
    for (int p = 0; p < 9; ++p) {
        const int kh = p / 3, kw = p - kh * 3;
        const u16* ap = xs + (kh * 34 + kw + Mtile * 16 + l15) * 264 + quad * 8;
        #pragma unroll
        for (int ck = 0; ck < 8; ++ck) {
            const int kk = p * 8 + ck;
            const bf16x8 av = *(const bf16x8*)(ap + ck * 32);
            const u16* wp = wsh + ((size_t)(kk * 12 + tg0) * 64 + lane) * 8;
            const bf16x8 b0 = *(const bf16x8*)(wp);
            const bf16x8 b1 = *(const bf16x8*)(wp + 512);
            const bf16x8 b2 = *(const bf16x8*)(wp + 1024);
            acc[0] = __builtin_amdgcn_mfma_f32_16x16x32_bf16(av, b0, acc[0], 0, 0, 0);
            acc[1] = __builtin_amdgcn_mfma_f32_16x16x32_bf16(av, b1, acc[1], 0, 0, 0);
            acc[2] = __builtin_amdgcn_mfma_f32_16x16x32_bf16(av, b2, acc[2], 0, 0, 0);
        }
    }

    const int px0 = Mtile * 16 + quad * 4;
    const int fl = *flag;
    #pragma unroll
    for (int ti = 0; ti < 3; ++ti) {
        const int co = (tg0 + ti) * 16 + l15;
        const float bias = cbf[co];
        #pragma unroll
        for (int r = 0; r < 4; ++r) {
            const size_t oidx = ((size_t)row * 32 + px0 + r) * 256 + co;
            const float v = acc[ti][r] + bias;
            if (fl) ((u16*)out)[oidx] = f2bf(v);
            else    ((float*)out)[oidx] = v;
        }
    }
}

// ---------------------------------------------------------------------------
// Attention stage 1: 4-way key split. FIX vs R8: NO unroll on the hk8 loop
// (the R8 full unroll spilled 300+ MB of scratch -> 277 us). Body = R6
// verified inner loop.
// ---------------------------------------------------------------------------
__global__ __launch_bounds__(256) void attn_part_kernel(
    const float* __restrict__ kbuf, const float* __restrict__ qbuf, const float* __restrict__ vbuf,
    const float* __restrict__ krw, const float* __restrict__ krh,
    float* __restrict__ lpart, float* __restrict__ vpart)
{
    const int q4 = blockIdx.x, bn = blockIdx.y, ksp = blockIdx.z;
    const int t = threadIdx.x;
    __shared__ float sK[2048];
    __shared__ float sV[2048];
    {
        const float4* kg = (const float4*)(kbuf + (size_t)bn * 8192 + ksp * 2048);
        const float4* vg = (const float4*)(vbuf + (size_t)bn * 8192 + ksp * 2048);
        float4* sk4 = (float4*)sK; float4* sv4 = (float4*)sV;
        #pragma unroll
        for (int k = 0; k < 2; k++) {
            int idx = t + k * 256;
            sk4[idx] = kg[idx];
            sv4[idx] = vg[idx];
        }
    }
    __syncthreads();

    const int i = q4 * 256 + t;
    const int hq = i >> 5, wq = i & 31;
    float q[8];
    const float* qg = qbuf + ((size_t)bn * 1024 + i) * 8;
    #pragma unroll
    for (int d = 0; d < 8; d++) q[d] = qg[d];

    float rw[32];
    #pragma unroll
    for (int wk = 0; wk < 32; wk++) {
        const float4* kp = (const float4*)(krw + (size_t)(wk - wq + 31) * 8);
        float4 a = kp[0], c = kp[1];
        rw[wk] = q[0]*a.x + q[1]*a.y + q[2]*a.z + q[3]*a.w
               + q[4]*c.x + q[5]*c.y + q[6]*c.z + q[7]*c.w;
    }

    float l = 0.f;
    float vacc[8] = {0.f,0.f,0.f,0.f,0.f,0.f,0.f,0.f};
    for (int hk8 = 0; hk8 < 8; hk8++) {          // NOT unrolled (spill fix)
        const int hk = ksp * 8 + hk8;
        const float4* hp = (const float4*)(krh + (size_t)(hk - hq + 31) * 8);
        float4 a = hp[0], c = hp[1];
        const float rh = q[0]*a.x + q[1]*a.y + q[2]*a.z + q[3]*a.w
                       + q[4]*c.x + q[5]*c.y + q[6]*c.z + q[7]*c.w;
        const float4* kr = (const float4*)sK + hk8 * 64;
        const float4* vr = (const float4*)sV + hk8 * 64;
        #pragma unroll
        for (int wk = 0; wk < 32; wk++) {
            float4 k0 = kr[2*wk], k1 = kr[2*wk+1];
            float s = q[0]*k0.x + q[1]*k0.y + q[2]*k0.z + q[3]*k0.w
                    + q[4]*k1.x + q[5]*k1.y + q[6]*k1.z + q[7]*k1.w + rw[wk] + rh;
            s = fminf(s, 60.0f);
            float p = __expf(s);
            l += p;
            float4 v0 = vr[2*wk], v1 = vr[2*wk+1];
            vacc[0] += p*v0.x; vacc[1] += p*v0.y; vacc[2] += p*v0.z; vacc[3] += p*v0.w;
            vacc[4] += p*v1.x; vacc[5] += p*v1.y; vacc[6] += p*v1.z; vacc[7] += p*v1.w;
        }
    }

    const size_t slot = ((size_t)ksp * 64 + bn) * 1024 + i;
    lpart[slot] = l;
    float* vp = vpart + slot * 8;
    #pragma unroll
    for (int d = 0; d < 8; d++) vp[d] = vacc[d];
}

// ---------------------------------------------------------------------------
// Attention stage 2 (VERIFIED R8): merge partials, normalize.
// ---------------------------------------------------------------------------
__global__ __launch_bounds__(256) void attn_fin_kernel(
    const float* __restrict__ lpart, const float* __restrict__ vpart,
    float* __restrict__ attnbuf)
{
    const int g = blockIdx.x * 256 + threadIdx.x;
    const int bn = g >> 13, rem = g & 8191;
    const int i = rem >> 3, d = rem & 7;
    float l = 0.f, v = 0.f;
    #pragma unroll
    for (int ks = 0; ks < 4; ks++) {
        const size_t slot = ((size_t)ks * 64 + bn) * 1024 + i;
        l += lpart[slot];
        v += vpart[slot * 8 + d];
    }
    const int b = bn >> 3, n = bn & 7;
    attnbuf[((size_t)b * 1024 + i) * 64 + n * 8 + d] = v / fmaxf(l, 1e-30f);
}

// ---------------------------------------------------------------------------
// Output projection (VERIFIED — unchanged).
// ---------------------------------------------------------------------------
__global__ __launch_bounds__(256) void proj_kernel(
    const float* __restrict__ attnbuf, const float* __restrict__ awf, const float* __restrict__ abf,
    const int* __restrict__ flag, void* __restrict__ out)
{
    const int g = blockIdx.x * 256 + threadIdx.x;
    const int px = g >> 6, o = g & 63;
    const float* ar = attnbuf + (size_t)px * 64;
    float acc = abf[o];
    #pragma unroll 8
    for (int c = 0; c < 64; c++) acc += ar[c] * awf[c * 64 + o];
    if (*flag) ((u16*)out)[(size_t)px * 256 + 192 + o] = f2bf(acc);
    else       ((float*)out)[(size_t)px * 256 + 192 + o] = acc;
}

// ---------------------------------------------------------------------------
extern "C" void kernel_launch(void* const* d_in, const int* in_sizes, int n_in,
                              void* d_out, int out_size, void* d_ws, size_t ws_size,
                              hipStream_t stream)
{
    float* ws = (float*)d_ws;
    int*   flag = (int*)(ws + FLAG_OFF);
    float* xf   = ws + XF_OFF;
    u16*   wsh  = (u16*)(ws + WSH_OFF);
    float* qwf  = ws + QWF_OFF;
    float* awf  = ws + AWF_OFF;
    float* cbf  = ws + CBF_OFF;
    float* qbf  = ws + QBF_OFF;
    float* abf  = ws + ABF_OFF;
    float* krw  = ws + KRW_OFF;
    float* krh  = ws + KRH_OFF;
    float* kbuf = ws + KB_OFF;
    float* qbuf = ws + QB_OFF;
    float* vbuf = ws + VB_OFF;
    float* atb  = ws + AT_OFF;
    float* lpart = ws + LP_OFF;
    float* vpart = ws + VP_OFF;
    u16*   wshQ  = (u16*)(ws + WSHQ_OFF);

    detect_kernel<<<1, 256, 0, stream>>>((const u16*)d_in[0], flag);

    cvt_all_kernel<<<8406, 256, 0, stream>>>(
        d_in[0], d_in[2], d_in[3], d_in[4], d_in[5], d_in[6], d_in[7], d_in[8],
        xf, cbf, qwf, qbf, awf, abf, krw, krh, flag);
    wshufC_kernel<<<216, 256, 0, stream>>>(d_in[1], wsh, flag);
    wshufQ_kernel<<<24,  256, 0, stream>>>(d_in[3], wshQ, flag);

    qkv_mfma_kernel <<<dim3(2, 256),   256, 0, stream>>>(xf, wshQ, qbf, kbuf, qbuf, vbuf);
    conv_mfma_kernel<<<dim3(2, 256),   256, 0, stream>>>(xf, wsh, cbf, flag, d_out);
    attn_part_kernel<<<dim3(4, 64, 4), 256, 0, stream>>>(kbuf, qbuf, vbuf, krw, krh, lpart, vpart);
    attn_fin_kernel <<<2048,           256, 0, stream>>>(lpart, vpart, atb);
    proj_kernel     <<<2048,           256, 0, stream>>>(atb, awf, abf, flag, d_out);
}

// Round 10
// 193.595 us; speedup vs baseline: 2.3807x; 1.1513x over previous
//
#include <hip/hip_runtime.h>
#include <cstdint>

using u16 = unsigned short;
using u32 = uint32_t;

typedef __attribute__((ext_vector_type(8))) short bf16x8;   // 8 bf16 = 4 VGPRs
typedef __attribute__((ext_vector_type(4))) float f32x4;    // MFMA accumulator

__device__ __forceinline__ float bf2f(u16 v) { return __uint_as_float(((u32)v) << 16); }
__device__ __forceinline__ u16 f2bf(float f) {
    u32 u = __float_as_uint(f);
    u += 0x7fffu + ((u >> 16) & 1u);   // RNE
    return (u16)(u >> 16);
}
__device__ __forceinline__ float2 pfma(float2 a, float2 b, float2 c) {
    return make_float2(fmaf(a.x, b.x, c.x), fmaf(a.y, b.y, c.y));   // -> v_pk_fma_f32 (hopefully)
}

// ---- workspace float offsets ----
#define FLAG_OFF 0
#define WSH_OFF  2097168   // conv weight bf16 fragments: u16[442368] = 221184 f
#define AWF_OFF  2588688   // 4096
#define CBF_OFF  2592784   // 192
#define QBF_OFF  2592976   // 192
#define ABF_OFF  2593168   // 64
#define KRW_OFF  2593232   // 504
#define KRH_OFF  2593736   // 504
#define KB_OFF   2594240   // 524288
#define QB_OFF   3118528   // 524288
#define VB_OFF   3642816   // 524288
#define AT_OFF   4167104   // 524288
#define LP_OFF   4691392   // attn l partials: 8*64*1024 = 524288
#define VP_OFF   5215680   // attn v partials: 4194304
#define WSHQ_OFF 9409984   // qkv weight bf16 fragments: u16[49152] = 24576 f
                           // end 9434560 floats ~ 37.7 MB (44 MB proven in R6)

// ---------------------------------------------------------------------------
// Dtype sniffer (verified; returns 0 on this problem's fp32 inputs).
// ---------------------------------------------------------------------------
__global__ void detect_kernel(const u16* __restrict__ x, int* __restrict__ flag) {
    __shared__ int cnt;
    if (threadIdx.x == 0) cnt = 0;
    __syncthreads();
    int c = 0;
    #pragma unroll
    for (int k = 0; k < 16; k++) {
        u16 v = x[threadIdx.x * 16 + k];
        int e = (v >> 7) & 0xFF;
        c += (e >= 110 && e <= 140) ? 1 : 0;
    }
    atomicAdd(&cnt, c);
    __syncthreads();
    if (threadIdx.x == 0) *flag = (cnt > 3300) ? 1 : 0;   // 1 = bf16 inputs
}

// ---------------------------------------------------------------------------
// Normalize SMALL tensors to fp32 (x and qkv_w now consumed raw elsewhere).
// ---------------------------------------------------------------------------
__global__ __launch_bounds__(256) void cvt_all_kernel(
    const void* __restrict__ cb, const void* __restrict__ qb, const void* __restrict__ aw,
    const void* __restrict__ ab, const void* __restrict__ kw_, const void* __restrict__ kh_,
    float* __restrict__ cbf, float* __restrict__ qbf, float* __restrict__ awf,
    float* __restrict__ abf, float* __restrict__ krw, float* __restrict__ krh,
    const int* __restrict__ flag)
{
    const int gid = blockIdx.x * 256 + threadIdx.x;
    const void* src; float* dst; int e;
    if      (gid <  192) { src = cb;  dst = cbf; e = gid; }
    else if (gid <  384) { src = qb;  dst = qbf; e = gid - 192; }
    else if (gid < 4480) { src = aw;  dst = awf; e = gid - 384; }
    else if (gid < 4544) { src = ab;  dst = abf; e = gid - 4480; }
    else if (gid < 5048) { src = kw_; dst = krw; e = gid - 4544; }
    else if (gid < 5552) { src = kh_; dst = krh; e = gid - 5048; }
    else return;
    dst[e] = (*flag) ? bf2f(((const u16*)src)[e]) : ((const float*)src)[e];
}

// ---------------------------------------------------------------------------
// Weight shuffles into MFMA B-fragment order, flag-adaptive reads. VERIFIED.
// ---------------------------------------------------------------------------
__global__ __launch_bounds__(256) void wshufC_kernel(
    const void* __restrict__ w, u16* __restrict__ o, const int* __restrict__ flag)
{
    const int g = blockIdx.x * 256 + threadIdx.x;          // 0..55295
    const int kk = g / 768, rem = g % 768;
    const int tile = rem >> 6, lane = rem & 63;
    const int n = tile * 16 + (lane & 15);
    const int fl = *flag;
    u16 tmp[8];
    #pragma unroll
    for (int j = 0; j < 8; j++) {
        const size_t k = (size_t)(kk * 32 + ((lane >> 4) << 3) + j);
        tmp[j] = fl ? ((const u16*)w)[k * 192 + n]
                    : f2bf(((const float*)w)[k * 192 + n]);
    }
    *(uint4*)(o + (size_t)g * 8) = *(const uint4*)tmp;
}

__global__ __launch_bounds__(256) void wshufQ_kernel(
    const void* __restrict__ w, u16* __restrict__ o, const int* __restrict__ flag)
{
    const int g = blockIdx.x * 256 + threadIdx.x;          // 0..6143
    const int kk = g / 768, rem = g % 768;
    const int tile = rem >> 6, lane = rem & 63;
    const int n = tile * 16 + (lane & 15);
    const int fl = *flag;
    u16 tmp[8];
    #pragma unroll
    for (int j = 0; j < 8; j++) {
        const size_t k = (size_t)(kk * 32 + ((lane >> 4) << 3) + j);
        tmp[j] = fl ? ((const u16*)w)[k * 192 + n]
                    : f2bf(((const float*)w)[k * 192 + n]);
    }
    *(uint4*)(o + (size_t)g * 8) = *(const uint4*)tmp;
}

// ---------------------------------------------------------------------------
// QKV implicit GEMM, bf16 MFMA. VERIFIED R9; changes: raw-input staging
// (flag-adaptive; fp32 path identical to R9), q scale *= log2(e) for the
// log2-domain softmax downstream.
// ---------------------------------------------------------------------------
__global__ __launch_bounds__(256) void qkv_mfma_kernel(
    const void* __restrict__ xr, const u16* __restrict__ wsh, const float* __restrict__ qbf,
    const int* __restrict__ flag,
    float* __restrict__ kbuf, float* __restrict__ qbuf, float* __restrict__ vbuf)
{
    const int coh = blockIdx.x, row = blockIdx.y;
    const int b = row >> 5, h = row & 31;
    const int t = threadIdx.x;
    __shared__ u16 xs[32 * 264];                            // 16896 B
    const int fl = *flag;

    if (fl) {
        const u16* src = (const u16*)xr + (size_t)row * 8192;
        #pragma unroll
        for (int i = 0; i < 4; ++i) {
            const int idx = t + i * 256;                    // 0..1023
            const int px = idx >> 5, cq = idx & 31;
            *(uint4*)(xs + px * 264 + cq * 8) = *(const uint4*)(src + px * 256 + cq * 8);
        }
    } else {
        const float* src = (const float*)xr + (size_t)row * 8192;
        #pragma unroll
        for (int i = 0; i < 8; ++i) {
            const int idx = t + i * 256;                    // 0..2047
            const int px = idx >> 6, c4 = idx & 63;
            float4 v = *(const float4*)(src + px * 256 + c4 * 4);
            u32 lo = (u32)f2bf(v.x) | ((u32)f2bf(v.y) << 16);
            u32 hi = (u32)f2bf(v.z) | ((u32)f2bf(v.w) << 16);
            *(uint2*)(xs + px * 264 + c4 * 4) = make_uint2(lo, hi);
        }
    }
    __syncthreads();

    const int lane = t & 63, wave = t >> 6;
    const int Mtile = wave & 1;
    const int tg0 = coh * 6 + (wave >> 1) * 3;
    const int l15 = lane & 15, quad = lane >> 4;

    f32x4 acc[3] = {{0,0,0,0},{0,0,0,0},{0,0,0,0}};

    const u16* ap = xs + (Mtile * 16 + l15) * 264 + quad * 8;
    #pragma unroll
    for (int kk = 0; kk < 8; ++kk) {
        const bf16x8 av = *(const bf16x8*)(ap + kk * 32);
        const u16* wp = wsh + ((size_t)(kk * 12 + tg0) * 64 + lane) * 8;
        const bf16x8 b0 = *(const bf16x8*)(wp);
        const bf16x8 b1 = *(const bf16x8*)(wp + 512);
        const bf16x8 b2 = *(const bf16x8*)(wp + 1024);
        acc[0] = __builtin_amdgcn_mfma_f32_16x16x32_bf16(av, b0, acc[0], 0, 0, 0);
        acc[1] = __builtin_amdgcn_mfma_f32_16x16x32_bf16(av, b1, acc[1], 0, 0, 0);
        acc[2] = __builtin_amdgcn_mfma_f32_16x16x32_bf16(av, b2, acc[2], 0, 0, 0);
    }

    // D layout (verified): col = lane&15, row = quad*4 + reg
    const int px0 = Mtile * 16 + quad * 4;
    #pragma unroll
    for (int ti = 0; ti < 3; ++ti) {
        const int tg = tg0 + ti;
        const int o = tg * 16 + l15;
        const int third = tg >> 2;                          // 0=k,1=q,2=v
        const int within = o - third * 64;
        const int n = within >> 3, d = within & 7;
        const float bias = qbf[o];
        // q scale = 8^-0.5 * log2(e): softmax runs in log2 domain (exp2)
        const float scale = (third == 1) ? 0.51006973050f : 1.0f;
        float* dst = (third == 0) ? kbuf : (third == 1) ? qbuf : vbuf;
        #pragma unroll
        for (int r = 0; r < 4; ++r) {
            const int i = h * 32 + px0 + r;
            dst[((size_t)(b * 8 + n) * 1024 + i) * 8 + d] = (acc[ti][r] + bias) * scale;
        }
    }
}

// ---------------------------------------------------------------------------
// Conv 3x3 implicit GEMM, bf16 MFMA. VERIFIED R9; change: raw-input staging
// (flag-adaptive; fp32 path identical to R9).
// ---------------------------------------------------------------------------
__global__ __launch_bounds__(256) void conv_mfma_kernel(
    const void* __restrict__ xr, const u16* __restrict__ wsh, const float* __restrict__ cbf,
    const int* __restrict__ flag, void* __restrict__ out)
{
    const int coh = blockIdx.x, row = blockIdx.y;
    const int b = row >> 5, h = row & 31;
    const int t = threadIdx.x;
    __shared__ u16 xs[3 * 34 * 264];                        // 53856 B
    const int fl = *flag;

    #pragma unroll
    for (int r = 0; r < 3; ++r) {
        const int hh = h + r - 1;
        if (t < 64) {                                       // zero border cols s=0, s=33
            const int s = (t >> 5) ? 33 : 0, cq = t & 31;
            *(uint4*)(xs + (r * 34 + s) * 264 + cq * 8) = make_uint4(0, 0, 0, 0);
        }
        const bool ok = (hh >= 0) && (hh < 32);
        const size_t base = ((size_t)((b * 32 + (ok ? hh : 0)) * 32)) * 256;
        if (fl) {
            const u16* src = (const u16*)xr + base;
            #pragma unroll
            for (int i = 0; i < 4; ++i) {
                const int idx = t + i * 256;                // 0..1023
                const int px = idx >> 5, cq = idx & 31;
                uint4 v = ok ? *(const uint4*)(src + px * 256 + cq * 8)
                             : make_uint4(0, 0, 0, 0);
                *(uint4*)(xs + (r * 34 + 1 + px) * 264 + cq * 8) = v;
            }
        } else {
            const float* src = (const float*)xr + base;
            #pragma unroll
            for (int i = 0; i < 8; ++i) {
                const int idx = t + i * 256;                // 0..2047
                const int px = idx >> 6, c4 = idx & 63;
                float4 v = ok ? *(const float4*)(src + px * 256 + c4 * 4)
                              : make_float4(0.f, 0.f, 0.f, 0.f);
                u32 lo = (u32)f2bf(v.x) | ((u32)f2bf(v.y) << 16);
                u32 hi = (u32)f2bf(v.z) | ((u32)f2bf(v.w) << 16);
                *(uint2*)(xs + (r * 34 + 1 + px) * 264 + c4 * 4) = make_uint2(lo, hi);
            }
        }
    }
    __syncthreads();

    const int lane = t & 63, wave = t >> 6;
    const int Mtile = wave & 1;
    const int tg0 = coh * 6 + (wave >> 1) * 3;
    const int l15 = lane & 15, quad = lane >> 4;

    f32x4 acc[3] = {{0,0,0,0},{0,0,0,0},{0,0,0,0}};

    #pragma unroll
    for (int p = 0; p < 9; ++p) {
        const int kh = p / 3, kw = p - kh * 3;
        const u16* ap = xs + (kh * 34 + kw + Mtile * 16 + l15) * 264 + quad * 8;
        #pragma unroll
        for (int ck = 0; ck < 8; ++ck) {
            const int kk = p * 8 + ck;
            const bf16x8 av = *(const bf16x8*)(ap + ck * 32);
            const u16* wp = wsh + ((size_t)(kk * 12 + tg0) * 64 + lane) * 8;
            const bf16x8 b0 = *(const bf16x8*)(wp);
            const bf16x8 b1 = *(const bf16x8*)(wp + 512);
            const bf16x8 b2 = *(const bf16x8*)(wp + 1024);
            acc[0] = __builtin_amdgcn_mfma_f32_16x16x32_bf16(av, b0, acc[0], 0, 0, 0);
            acc[1] = __builtin_amdgcn_mfma_f32_16x16x32_bf16(av, b1, acc[1], 0, 0, 0);
            acc[2] = __builtin_amdgcn_mfma_f32_16x16x32_bf16(av, b2, acc[2], 0, 0, 0);
        }
    }

    const int px0 = Mtile * 16 + quad * 4;
    #pragma unroll
    for (int ti = 0; ti < 3; ++ti) {
        const int co = (tg0 + ti) * 16 + l15;
        const float bias = cbf[co];
        #pragma unroll
        for (int r = 0; r < 4; ++r) {
            const size_t oidx = ((size_t)row * 32 + px0 + r) * 256 + co;
            const float v = acc[ti][r] + bias;
            if (fl) ((u16*)out)[oidx] = f2bf(v);
            else    ((float*)out)[oidx] = v;
        }
    }
}

// ---------------------------------------------------------------------------
// Attention stage 1: 8-way key split (R9-verified structure). Log2-domain
// (q pre-scaled by log2e -> bare exp2), float2/packed-fp32 arithmetic.
// grid (4,64,8) = 2048 blocks, 8 KB LDS. Outer hk loop NOT unrolled (R8 spill).
// ---------------------------------------------------------------------------
__global__ __launch_bounds__(256) void attn_part_kernel(
    const float* __restrict__ kbuf, const float* __restrict__ qbuf, const float* __restrict__ vbuf,
    const float* __restrict__ krw, const float* __restrict__ krh,
    float* __restrict__ lpart, float* __restrict__ vpart)
{
    const int q4 = blockIdx.x, bn = blockIdx.y, ksp = blockIdx.z;
    const int t = threadIdx.x;
    __shared__ float sK[1024];
    __shared__ float sV[1024];
    {
        const float4* kg = (const float4*)(kbuf + (size_t)bn * 8192 + ksp * 1024);
        const float4* vg = (const float4*)(vbuf + (size_t)bn * 8192 + ksp * 1024);
        ((float4*)sK)[t] = kg[t];
        ((float4*)sV)[t] = vg[t];
    }
    __syncthreads();

    const int i = q4 * 256 + t;
    const int hq = i >> 5, wq = i & 31;
    float2 q2[4];
    {
        const float4* qg = (const float4*)(qbuf + ((size_t)bn * 1024 + i) * 8);
        float4 qa = qg[0], qb = qg[1];
        q2[0] = make_float2(qa.x, qa.y); q2[1] = make_float2(qa.z, qa.w);
        q2[2] = make_float2(qb.x, qb.y); q2[3] = make_float2(qb.z, qb.w);
    }

    float rw[32];
    #pragma unroll
    for (int wk = 0; wk < 32; wk++) {
        const float4* kp = (const float4*)(krw + (size_t)(wk - wq + 31) * 8);
        float4 a = kp[0], c = kp[1];
        float2 d2 = pfma(q2[0], make_float2(a.x, a.y),
                    pfma(q2[1], make_float2(a.z, a.w),
                    pfma(q2[2], make_float2(c.x, c.y),
                    pfma(q2[3], make_float2(c.z, c.w), make_float2(0.f, 0.f)))));
        rw[wk] = d2.x + d2.y;
    }

    float l = 0.f;
    float2 va01 = {0,0}, va23 = {0,0}, va45 = {0,0}, va67 = {0,0};
    for (int hk4 = 0; hk4 < 4; hk4++) {          // NOT unrolled (spill guard)
        const int hk = ksp * 4 + hk4;
        float rh;
        {
            const float4* hp = (const float4*)(krh + (size_t)(hk - hq + 31) * 8);
            float4 a = hp[0], c = hp[1];
            float2 d2 = pfma(q2[0], make_float2(a.x, a.y),
                        pfma(q2[1], make_float2(a.z, a.w),
                        pfma(q2[2], make_float2(c.x, c.y),
                        pfma(q2[3], make_float2(c.z, c.w), make_float2(0.f, 0.f)))));
            rh = d2.x + d2.y;
        }
        const float4* kr = (const float4*)sK + hk4 * 64;
        const float4* vr = (const float4*)sV + hk4 * 64;
        #pragma unroll
        for (int wk = 0; wk < 32; wk++) {
            float4 k0 = kr[2*wk], k1 = kr[2*wk+1];
            float2 acc2 = pfma(q2[0], make_float2(k0.x, k0.y),
                          pfma(q2[1], make_float2(k0.z, k0.w),
                          pfma(q2[2], make_float2(k1.x, k1.y),
                          pfma(q2[3], make_float2(k1.z, k1.w),
                               make_float2(rw[wk] + rh, 0.f)))));
            float s = fminf(acc2.x + acc2.y, 80.0f);   // log2-domain clamp
            float p = exp2f(s);
            l += p;
            float4 v0 = vr[2*wk], v1 = vr[2*wk+1];
            float2 p2 = make_float2(p, p);
            va01 = pfma(p2, make_float2(v0.x, v0.y), va01);
            va23 = pfma(p2, make_float2(v0.z, v0.w), va23);
            va45 = pfma(p2, make_float2(v1.x, v1.y), va45);
            va67 = pfma(p2, make_float2(v1.z, v1.w), va67);
        }
    }

    const size_t slot = ((size_t)ksp * 64 + bn) * 1024 + i;
    lpart[slot] = l;
    float* vp = vpart + slot * 8;
    vp[0] = va01.x; vp[1] = va01.y; vp[2] = va23.x; vp[3] = va23.y;
    vp[4] = va45.x; vp[5] = va45.y; vp[6] = va67.x; vp[7] = va67.y;
}

// ---------------------------------------------------------------------------
// Attention stage 2: merge 8 key-split partials, normalize.
// ---------------------------------------------------------------------------
__global__ __launch_bounds__(256) void attn_fin_kernel(
    const float* __restrict__ lpart, const float* __restrict__ vpart,
    float* __restrict__ attnbuf)
{
    const int g = blockIdx.x * 256 + threadIdx.x;
    const int bn = g >> 13, rem = g & 8191;
    const int i = rem >> 3, d = rem & 7;
    float l = 0.f, v = 0.f;
    #pragma unroll
    for (int ks = 0; ks < 8; ks++) {
        const size_t slot = ((size_t)ks * 64 + bn) * 1024 + i;
        l += lpart[slot];
        v += vpart[slot * 8 + d];
    }
    const int b = bn >> 3, n = bn & 7;
    attnbuf[((size_t)b * 1024 + i) * 64 + n * 8 + d] = v / fmaxf(l, 1e-30f);
}

// ---------------------------------------------------------------------------
// Output projection (VERIFIED — unchanged).
// ---------------------------------------------------------------------------
__global__ __launch_bounds__(256) void proj_kernel(
    const float* __restrict__ attnbuf, const float* __restrict__ awf, const float* __restrict__ abf,
    const int* __restrict__ flag, void* __restrict__ out)
{
    const int g = blockIdx.x * 256 + threadIdx.x;
    const int px = g >> 6, o = g & 63;
    const float* ar = attnbuf + (size_t)px * 64;
    float acc = abf[o];
    #pragma unroll 8
    for (int c = 0; c < 64; c++) acc += ar[c] * awf[c * 64 + o];
    if (*flag) ((u16*)out)[(size_t)px * 256 + 192 + o] = f2bf(acc);
    else       ((float*)out)[(size_t)px * 256 + 192 + o] = acc;
}

// ---------------------------------------------------------------------------
extern "C" void kernel_launch(void* const* d_in, const int* in_sizes, int n_in,
                              void* d_out, int out_size, void* d_ws, size_t ws_size,
                              hipStream_t stream)
{
    float* ws = (float*)d_ws;
    int*   flag = (int*)(ws + FLAG_OFF);
    u16*   wsh  = (u16*)(ws + WSH_OFF);
    float* awf  = ws + AWF_OFF;
    float* cbf  = ws + CBF_OFF;
    float* qbf  = ws + QBF_OFF;
    float* abf  = ws + ABF_OFF;
    float* krw  = ws + KRW_OFF;
    float* krh  = ws + KRH_OFF;
    float* kbuf = ws + KB_OFF;
    float* qbuf = ws + QB_OFF;
    float* vbuf = ws + VB_OFF;
    float* atb  = ws + AT_OFF;
    float* lpart = ws + LP_OFF;
    float* vpart = ws + VP_OFF;
    u16*   wshQ  = (u16*)(ws + WSHQ_OFF);

    detect_kernel<<<1, 256, 0, stream>>>((const u16*)d_in[0], flag);

    cvt_all_kernel<<<22, 256, 0, stream>>>(
        d_in[2], d_in[4], d_in[5], d_in[6], d_in[7], d_in[8],
        cbf, qbf, awf, abf, krw, krh, flag);
    wshufC_kernel<<<216, 256, 0, stream>>>(d_in[1], wsh, flag);
    wshufQ_kernel<<<24,  256, 0, stream>>>(d_in[3], wshQ, flag);

    qkv_mfma_kernel <<<dim3(2, 256),   256, 0, stream>>>(d_in[0], wshQ, qbf, flag, kbuf, qbuf, vbuf);
    conv_mfma_kernel<<<dim3(2, 256),   256, 0, stream>>>(d_in[0], wsh, cbf, flag, d_out);
    attn_part_kernel<<<dim3(4, 64, 8), 256, 0, stream>>>(kbuf, qbuf, vbuf, krw, krh, lpart, vpart);
    attn_fin_kernel <<<2048,           256, 0, stream>>>(lpart, vpart, atb);
    proj_kernel     <<<2048,           256, 0, stream>>>(atb, awf, abf, flag, d_out);
}

// Round 11
// 184.126 us; speedup vs baseline: 2.5031x; 1.0514x over previous
//
#include <hip/hip_runtime.h>
#include <cstdint>

using u16 = unsigned short;
using u32 = uint32_t;

typedef __attribute__((ext_vector_type(8))) short bf16x8;   // 8 bf16 = 4 VGPRs
typedef __attribute__((ext_vector_type(4))) float f32x4;    // MFMA accumulator

__device__ __forceinline__ float bf2f(u16 v) { return __uint_as_float(((u32)v) << 16); }
__device__ __forceinline__ u16 f2bf(float f) {
    u32 u = __float_as_uint(f);
    u += 0x7fffu + ((u >> 16) & 1u);   // RNE
    return (u16)(u >> 16);
}

// ---- workspace float offsets ----
#define FLAG_OFF 0
#define WSH_OFF  2097168   // conv weight bf16 fragments: u16[442368] = 221184 f
#define AWF_OFF  2588688   // 4096
#define CBF_OFF  2592784   // 192
#define QBF_OFF  2592976   // 192
#define ABF_OFF  2593168   // 64
#define KRW_OFF  2593232   // 504
#define KRH_OFF  2593736   // 504
#define KB_OFF   2594240   // 524288
#define QB_OFF   3118528   // 524288
#define VB_OFF   3642816   // 524288
#define AT_OFF   4167104   // 524288
#define WSHQ_OFF 9409984   // qkv weight bf16 fragments: u16[49152] = 24576 f

// ---------------------------------------------------------------------------
// Dtype sniffer (verified; returns 0 on this problem's fp32 inputs).
// ---------------------------------------------------------------------------
__global__ void detect_kernel(const u16* __restrict__ x, int* __restrict__ flag) {
    __shared__ int cnt;
    if (threadIdx.x == 0) cnt = 0;
    __syncthreads();
    int c = 0;
    #pragma unroll
    for (int k = 0; k < 16; k++) {
        u16 v = x[threadIdx.x * 16 + k];
        int e = (v >> 7) & 0xFF;
        c += (e >= 110 && e <= 140) ? 1 : 0;
    }
    atomicAdd(&cnt, c);
    __syncthreads();
    if (threadIdx.x == 0) *flag = (cnt > 3300) ? 1 : 0;   // 1 = bf16 inputs
}

// ---------------------------------------------------------------------------
// Normalize SMALL tensors to fp32 (VERIFIED).
// ---------------------------------------------------------------------------
__global__ __launch_bounds__(256) void cvt_all_kernel(
    const void* __restrict__ cb, const void* __restrict__ qb, const void* __restrict__ aw,
    const void* __restrict__ ab, const void* __restrict__ kw_, const void* __restrict__ kh_,
    float* __restrict__ cbf, float* __restrict__ qbf, float* __restrict__ awf,
    float* __restrict__ abf, float* __restrict__ krw, float* __restrict__ krh,
    const int* __restrict__ flag)
{
    const int gid = blockIdx.x * 256 + threadIdx.x;
    const void* src; float* dst; int e;
    if      (gid <  192) { src = cb;  dst = cbf; e = gid; }
    else if (gid <  384) { src = qb;  dst = qbf; e = gid - 192; }
    else if (gid < 4480) { src = aw;  dst = awf; e = gid - 384; }
    else if (gid < 4544) { src = ab;  dst = abf; e = gid - 4480; }
    else if (gid < 5048) { src = kw_; dst = krw; e = gid - 4544; }
    else if (gid < 5552) { src = kh_; dst = krh; e = gid - 5048; }
    else return;
    dst[e] = (*flag) ? bf2f(((const u16*)src)[e]) : ((const float*)src)[e];
}

// ---------------------------------------------------------------------------
// Weight shuffles into MFMA B-fragment order, flag-adaptive reads. VERIFIED.
// ---------------------------------------------------------------------------
__global__ __launch_bounds__(256) void wshufC_kernel(
    const void* __restrict__ w, u16* __restrict__ o, const int* __restrict__ flag)
{
    const int g = blockIdx.x * 256 + threadIdx.x;          // 0..55295
    const int kk = g / 768, rem = g % 768;
    const int tile = rem >> 6, lane = rem & 63;
    const int n = tile * 16 + (lane & 15);
    const int fl = *flag;
    u16 tmp[8];
    #pragma unroll
    for (int j = 0; j < 8; j++) {
        const size_t k = (size_t)(kk * 32 + ((lane >> 4) << 3) + j);
        tmp[j] = fl ? ((const u16*)w)[k * 192 + n]
                    : f2bf(((const float*)w)[k * 192 + n]);
    }
    *(uint4*)(o + (size_t)g * 8) = *(const uint4*)tmp;
}

__global__ __launch_bounds__(256) void wshufQ_kernel(
    const void* __restrict__ w, u16* __restrict__ o, const int* __restrict__ flag)
{
    const int g = blockIdx.x * 256 + threadIdx.x;          // 0..6143
    const int kk = g / 768, rem = g % 768;
    const int tile = rem >> 6, lane = rem & 63;
    const int n = tile * 16 + (lane & 15);
    const int fl = *flag;
    u16 tmp[8];
    #pragma unroll
    for (int j = 0; j < 8; j++) {
        const size_t k = (size_t)(kk * 32 + ((lane >> 4) << 3) + j);
        tmp[j] = fl ? ((const u16*)w)[k * 192 + n]
                    : f2bf(((const float*)w)[k * 192 + n]);
    }
    *(uint4*)(o + (size_t)g * 8) = *(const uint4*)tmp;
}

// ---------------------------------------------------------------------------
// QKV implicit GEMM, bf16 MFMA. VERIFIED R10 — unchanged (q scale includes
// log2e for the log2-domain softmax).
// ---------------------------------------------------------------------------
__global__ __launch_bounds__(256) void qkv_mfma_kernel(
    const void* __restrict__ xr, const u16* __restrict__ wsh, const float* __restrict__ qbf,
    const int* __restrict__ flag,
    float* __restrict__ kbuf, float* __restrict__ qbuf, float* __restrict__ vbuf)
{
    const int coh = blockIdx.x, row = blockIdx.y;
    const int b = row >> 5, h = row & 31;
    const int t = threadIdx.x;
    __shared__ u16 xs[32 * 264];                            // 16896 B
    const int fl = *flag;

    if (fl) {
        const u16* src = (const u16*)xr + (size_t)row * 8192;
        #pragma unroll
        for (int i = 0; i < 4; ++i) {
            const int idx = t + i * 256;
            const int px = idx >> 5, cq = idx & 31;
            *(uint4*)(xs + px * 264 + cq * 8) = *(const uint4*)(src + px * 256 + cq * 8);
        }
    } else {
        const float* src = (const float*)xr + (size_t)row * 8192;
        #pragma unroll
        for (int i = 0; i < 8; ++i) {
            const int idx = t + i * 256;
            const int px = idx >> 6, c4 = idx & 63;
            float4 v = *(const float4*)(src + px * 256 + c4 * 4);
            u32 lo = (u32)f2bf(v.x) | ((u32)f2bf(v.y) << 16);
            u32 hi = (u32)f2bf(v.z) | ((u32)f2bf(v.w) << 16);
            *(uint2*)(xs + px * 264 + c4 * 4) = make_uint2(lo, hi);
        }
    }
    __syncthreads();

    const int lane = t & 63, wave = t >> 6;
    const int Mtile = wave & 1;
    const int tg0 = coh * 6 + (wave >> 1) * 3;
    const int l15 = lane & 15, quad = lane >> 4;

    f32x4 acc[3] = {{0,0,0,0},{0,0,0,0},{0,0,0,0}};

    const u16* ap = xs + (Mtile * 16 + l15) * 264 + quad * 8;
    #pragma unroll
    for (int kk = 0; kk < 8; ++kk) {
        const bf16x8 av = *(const bf16x8*)(ap + kk * 32);
        const u16* wp = wsh + ((size_t)(kk * 12 + tg0) * 64 + lane) * 8;
        const bf16x8 b0 = *(const bf16x8*)(wp);
        const bf16x8 b1 = *(const bf16x8*)(wp + 512);
        const bf16x8 b2 = *(const bf16x8*)(wp + 1024);
        acc[0] = __builtin_amdgcn_mfma_f32_16x16x32_bf16(av, b0, acc[0], 0, 0, 0);
        acc[1] = __builtin_amdgcn_mfma_f32_16x16x32_bf16(av, b1, acc[1], 0, 0, 0);
        acc[2] = __builtin_amdgcn_mfma_f32_16x16x32_bf16(av, b2, acc[2], 0, 0, 0);
    }

    const int px0 = Mtile * 16 + quad * 4;
    #pragma unroll
    for (int ti = 0; ti < 3; ++ti) {
        const int tg = tg0 + ti;
        const int o = tg * 16 + l15;
        const int third = tg >> 2;                          // 0=k,1=q,2=v
        const int within = o - third * 64;
        const int n = within >> 3, d = within & 7;
        const float bias = qbf[o];
        const float scale = (third == 1) ? 0.51006973050f : 1.0f;  // 8^-.5 * log2e
        float* dst = (third == 0) ? kbuf : (third == 1) ? qbuf : vbuf;
        #pragma unroll
        for (int r = 0; r < 4; ++r) {
            const int i = h * 32 + px0 + r;
            dst[((size_t)(b * 8 + n) * 1024 + i) * 8 + d] = (acc[ti][r] + bias) * scale;
        }
    }
}

// ---------------------------------------------------------------------------
// Conv 3x3 implicit GEMM, bf16 MFMA. VERIFIED R10 — unchanged.
// ---------------------------------------------------------------------------
__global__ __launch_bounds__(256) void conv_mfma_kernel(
    const void* __restrict__ xr, const u16* __restrict__ wsh, const float* __restrict__ cbf,
    const int* __restrict__ flag, void* __restrict__ out)
{
    const int coh = blockIdx.x, row = blockIdx.y;
    const int b = row >> 5, h = row & 31;
    const int t = threadIdx.x;
    __shared__ u16 xs[3 * 34 * 264];                        // 53856 B
    const int fl = *flag;

    #pragma unroll
    for (int r = 0; r < 3; ++r) {
        const int hh = h + r - 1;
        if (t < 64) {
            const int s = (t >> 5) ? 33 : 0, cq = t & 31;
            *(uint4*)(xs + (r * 34 + s) * 264 + cq * 8) = make_uint4(0, 0, 0, 0);
        }
        const bool ok = (hh >= 0) && (hh < 32);
        const size_t base = ((size_t)((b * 32 + (ok ? hh : 0)) * 32)) * 256;
        if (fl) {
            const u16* src = (const u16*)xr + base;
            #pragma unroll
            for (int i = 0; i < 4; ++i) {
                const int idx = t + i * 256;
                const int px = idx >> 5, cq = idx & 31;
                uint4 v = ok ? *(const uint4*)(src + px * 256 + cq * 8)
                             : make_uint4(0, 0, 0, 0);
                *(uint4*)(xs + (r * 34 + 1 + px) * 264 + cq * 8) = v;
            }
        } else {
            const float* src = (const float*)xr + base;
            #pragma unroll
            for (int i = 0; i < 8; ++i) {
                const int idx = t + i * 256;
                const int px = idx >> 6, c4 = idx & 63;
                float4 v = ok ? *(const float4*)(src + px * 256 + c4 * 4)
                              : make_float4(0.f, 0.f, 0.f, 0.f);
                u32 lo = (u32)f2bf(v.x) | ((u32)f2bf(v.y) << 16);
                u32 hi = (u32)f2bf(v.z) | ((u32)f2bf(v.w) << 16);
                *(uint2*)(xs + (r * 34 + 1 + px) * 264 + c4 * 4) = make_uint2(lo, hi);
            }
        }
    }
    __syncthreads();

    const int lane = t & 63, wave = t >> 6;
    const int Mtile = wave & 1;
    const int tg0 = coh * 6 + (wave >> 1) * 3;
    const int l15 = lane & 15, quad = lane >> 4;

    f32x4 acc[3] = {{0,0,0,0},{0,0,0,0},{0,0,0,0}};

    #pragma unroll
    for (int p = 0; p < 9; ++p) {
        const int kh = p / 3, kw = p - kh * 3;
        const u16* ap = xs + (kh * 34 + kw + Mtile * 16 + l15) * 264 + quad * 8;
        #pragma unroll
        for (int ck = 0; ck < 8; ++ck) {
            const int kk = p * 8 + ck;
            const bf16x8 av = *(const bf16x8*)(ap + ck * 32);
            const u16* wp = wsh + ((size_t)(kk * 12 + tg0) * 64 + lane) * 8;
            const bf16x8 b0 = *(const bf16x8*)(wp);
            const bf16x8 b1 = *(const bf16x8*)(wp + 512);
            const bf16x8 b2 = *(const bf16x8*)(wp + 1024);
            acc[0] = __builtin_amdgcn_mfma_f32_16x16x32_bf16(av, b0, acc[0], 0, 0, 0);
            acc[1] = __builtin_amdgcn_mfma_f32_16x16x32_bf16(av, b1, acc[1], 0, 0, 0);
            acc[2] = __builtin_amdgcn_mfma_f32_16x16x32_bf16(av, b2, acc[2], 0, 0, 0);
        }
    }

    const int px0 = Mtile * 16 + quad * 4;
    #pragma unroll
    for (int ti = 0; ti < 3; ++ti) {
        const int co = (tg0 + ti) * 16 + l15;
        const float bias = cbf[co];
        #pragma unroll
        for (int r = 0; r < 4; ++r) {
            const size_t oidx = ((size_t)row * 32 + px0 + r) * 256 + co;
            const float v = acc[ti][r] + bias;
            if (fl) ((u16*)out)[oidx] = f2bf(v);
            else    ((float*)out)[oidx] = v;
        }
    }
}

// ---------------------------------------------------------------------------
// MFMA flash attention. Block = (head bn, 64 q-rows). 4 waves x 16 rows.
// Per 32-key chunk/wave: 2 QK MFMAs (qk-dim 8 zero-padded to 32; C-init = rh),
// 2 rel-w MFMAs (one-hot permutation B selects rw[row][wk] from bf16 table),
// exp2 -> bf16 P -> per-wave LDS (no barrier), 1 PV MFMA with V^T fragments +
// ones column (l lands in C col n=8). Normalize via shfl, write atb.
// Layouts: A[m=lane&15][k=quad*8+j], B[k=quad*8+j][n=lane&15],
// C[col=lane&15][row=quad*4+r] — all verified in this pipeline.
// ---------------------------------------------------------------------------
__global__ __launch_bounds__(256) void attn_mfma_kernel(
    const float* __restrict__ kbuf, const float* __restrict__ qbuf, const float* __restrict__ vbuf,
    const float* __restrict__ krw, const float* __restrict__ krh, float* __restrict__ attnbuf)
{
    const int qb = blockIdx.x;           // 0..15 (64 q-rows each)
    const int bn = blockIdx.y;           // 0..63
    const int b = bn >> 3, hn = bn & 7;
    const int t = threadIdx.x;
    const int i0 = qb * 64;

    __shared__ u16   sK [1024 * 8];      // [key][d] bf16          16384 B
    __shared__ u16   sVT[8 * 1032];      // [d][key] bf16 (pad)    16512 B
    __shared__ u16   sRW[64 * 40];       // [ilocal][wk] bf16      5120 B
    __shared__ float sRH[32 * 68];       // [hk][ilocal] f32       8704 B
    __shared__ u16   sP [4 * 16 * 56];   // per-wave P, stride 56  7168 B  (53888 total)

    // ---- stage K (linear bf16 copy) and V^T (transposed bf16) ----
    const float* kg = kbuf + (size_t)bn * 8192;
    const float* vg = vbuf + (size_t)bn * 8192;
    #pragma unroll
    for (int k8 = 0; k8 < 8; k8++) {
        const int idx = t + k8 * 256;                 // 0..2047 float4s
        float4 kv = ((const float4*)kg)[idx];
        u32 lo = (u32)f2bf(kv.x) | ((u32)f2bf(kv.y) << 16);
        u32 hi = (u32)f2bf(kv.z) | ((u32)f2bf(kv.w) << 16);
        *(uint2*)(sK + idx * 4) = make_uint2(lo, hi);
        float4 vv = ((const float4*)vg)[idx];
        const int key = idx >> 1, dbase = (idx & 1) * 4;
        sVT[(dbase + 0) * 1032 + key] = f2bf(vv.x);
        sVT[(dbase + 1) * 1032 + key] = f2bf(vv.y);
        sVT[(dbase + 2) * 1032 + key] = f2bf(vv.z);
        sVT[(dbase + 3) * 1032 + key] = f2bf(vv.w);
    }
    // ---- rel tables: rw (bf16, A-layout-friendly) and rh (f32, C-init) ----
    #pragma unroll
    for (int k8 = 0; k8 < 8; k8++) {
        const int idx = t + k8 * 256;                 // 0..2047
        const int il = idx >> 5, w = idx & 31;
        const int i = i0 + il;
        const float* q = qbuf + ((size_t)bn * 1024 + i) * 8;
        float4 qa = *(const float4*)q, qc = *(const float4*)(q + 4);
        const float* rp = krw + (size_t)(w - (i & 31) + 31) * 8;
        float4 ra = *(const float4*)rp, rc = *(const float4*)(rp + 4);
        sRW[il * 40 + w] = f2bf(qa.x*ra.x + qa.y*ra.y + qa.z*ra.z + qa.w*ra.w
                              + qc.x*rc.x + qc.y*rc.y + qc.z*rc.z + qc.w*rc.w);
        const float* hp = krh + (size_t)(w - (i >> 5) + 31) * 8;
        float4 ha = *(const float4*)hp, hc = *(const float4*)(hp + 4);
        sRH[w * 68 + il] = qa.x*ha.x + qa.y*ha.y + qa.z*ha.z + qa.w*ha.w
                         + qc.x*hc.x + qc.y*hc.y + qc.z*hc.z + qc.w*hc.w;
    }
    __syncthreads();

    const int lane = t & 63, wave = t >> 6;
    const int l15 = lane & 15, quad = lane >> 4;

    // A_q fragment: row = wave*16 + l15; real k only in quad 0 (qk-dim 8)
    union Frag { u16 a[8]; bf16x8 v; };
    Frag Aq;
    {
        const float* q = qbuf + ((size_t)bn * 1024 + i0 + wave * 16 + l15) * 8;
        float4 qa = *(const float4*)q, qc = *(const float4*)(q + 4);
        Aq.a[0] = f2bf(qa.x); Aq.a[1] = f2bf(qa.y); Aq.a[2] = f2bf(qa.z); Aq.a[3] = f2bf(qa.w);
        Aq.a[4] = f2bf(qc.x); Aq.a[5] = f2bf(qc.y); Aq.a[6] = f2bf(qc.z); Aq.a[7] = f2bf(qc.w);
        if (quad != 0) {
            #pragma unroll
            for (int j = 0; j < 8; j++) Aq.a[j] = 0;
        }
    }
    // A_rw fragment: rw[row][k=quad*8+j] (full k 0..31 used)
    const bf16x8 Arw = *(const bf16x8*)(sRW + (wave * 16 + l15) * 40 + quad * 8);

    // One-hot permutation B fragments: B[k][n] = (k == t16*16 + n)
    Frag P0, P1, ONE;
    #pragma unroll
    for (int j = 0; j < 8; j++) { P0.a[j] = 0; P1.a[j] = 0; ONE.a[j] = 0x3F80; }
    {
        const int h0 = l15 - quad * 8;
        if (h0 >= 0 && h0 < 8) P0.a[h0] = 0x3F80;
        const int h1 = 16 + l15 - quad * 8;
        if (h1 >= 0 && h1 < 8) P1.a[h1] = 0x3F80;
    }

    u16* pb = sP + wave * (16 * 56);
    f32x4 oacc = {0.f, 0.f, 0.f, 0.f};

    for (int chunk = 0; chunk < 32; chunk++) {
        // C-init with rh[row][hk=chunk]
        const float4 rh4 = *(const float4*)(sRH + chunk * 68 + wave * 16 + quad * 4);
        f32x4 acc0 = {rh4.x, rh4.y, rh4.z, rh4.w};
        f32x4 acc1 = acc0;
        // K fragments (broadcast read; quads 1-3 multiply A=0, value irrelevant)
        const bf16x8 bk0 = *(const bf16x8*)(sK + (chunk * 32 + l15) * 8);
        const bf16x8 bk1 = *(const bf16x8*)(sK + (chunk * 32 + 16 + l15) * 8);
        acc0 = __builtin_amdgcn_mfma_f32_16x16x32_bf16(Aq.v, bk0, acc0, 0, 0, 0);
        acc0 = __builtin_amdgcn_mfma_f32_16x16x32_bf16(Arw, P0.v, acc0, 0, 0, 0);
        acc1 = __builtin_amdgcn_mfma_f32_16x16x32_bf16(Aq.v, bk1, acc1, 0, 0, 0);
        acc1 = __builtin_amdgcn_mfma_f32_16x16x32_bf16(Arw, P1.v, acc1, 0, 0, 0);
        // P = exp2(S) in bf16, C layout -> per-wave LDS buffer
        #pragma unroll
        for (int r = 0; r < 4; r++) {
            const float p0 = exp2f(fminf(acc0[r], 80.0f));
            const float p1 = exp2f(fminf(acc1[r], 80.0f));
            pb[(quad * 4 + r) * 56 + l15]      = f2bf(p0);
            pb[(quad * 4 + r) * 56 + 16 + l15] = f2bf(p1);
        }
        // PV: A = P (A-layout read), B = V^T fragment (+ones col at n=8)
        const bf16x8 Ap = *(const bf16x8*)(pb + l15 * 56 + quad * 8);
        bf16x8 Bv;
        if (l15 < 8) Bv = *(const bf16x8*)(sVT + l15 * 1032 + chunk * 32 + quad * 8);
        else         Bv = ONE.v;   // n==8 -> l column; n>8 columns unused
        oacc = __builtin_amdgcn_mfma_f32_16x16x32_bf16(Ap, Bv, oacc, 0, 0, 0);
    }

    // normalize (l lives in lane n==8 of same quad) and write atb
    #pragma unroll
    for (int r = 0; r < 4; r++) {
        const float lr = __shfl(oacc[r], (lane & 48) | 8, 64);
        const float val = oacc[r] / fmaxf(lr, 1e-30f);
        if (l15 < 8) {
            const int i = i0 + wave * 16 + quad * 4 + r;
            attnbuf[((size_t)b * 1024 + i) * 64 + hn * 8 + l15] = val;
        }
    }
}

// ---------------------------------------------------------------------------
// Output projection (VERIFIED — unchanged).
// ---------------------------------------------------------------------------
__global__ __launch_bounds__(256) void proj_kernel(
    const float* __restrict__ attnbuf, const float* __restrict__ awf, const float* __restrict__ abf,
    const int* __restrict__ flag, void* __restrict__ out)
{
    const int g = blockIdx.x * 256 + threadIdx.x;
    const int px = g >> 6, o = g & 63;
    const float* ar = attnbuf + (size_t)px * 64;
    float acc = abf[o];
    #pragma unroll 8
    for (int c = 0; c < 64; c++) acc += ar[c] * awf[c * 64 + o];
    if (*flag) ((u16*)out)[(size_t)px * 256 + 192 + o] = f2bf(acc);
    else       ((float*)out)[(size_t)px * 256 + 192 + o] = acc;
}

// ---------------------------------------------------------------------------
extern "C" void kernel_launch(void* const* d_in, const int* in_sizes, int n_in,
                              void* d_out, int out_size, void* d_ws, size_t ws_size,
                              hipStream_t stream)
{
    float* ws = (float*)d_ws;
    int*   flag = (int*)(ws + FLAG_OFF);
    u16*   wsh  = (u16*)(ws + WSH_OFF);
    float* awf  = ws + AWF_OFF;
    float* cbf  = ws + CBF_OFF;
    float* qbf  = ws + QBF_OFF;
    float* abf  = ws + ABF_OFF;
    float* krw  = ws + KRW_OFF;
    float* krh  = ws + KRH_OFF;
    float* kbuf = ws + KB_OFF;
    float* qbuf = ws + QB_OFF;
    float* vbuf = ws + VB_OFF;
    float* atb  = ws + AT_OFF;
    u16*   wshQ = (u16*)(ws + WSHQ_OFF);

    detect_kernel<<<1, 256, 0, stream>>>((const u16*)d_in[0], flag);

    cvt_all_kernel<<<22, 256, 0, stream>>>(
        d_in[2], d_in[4], d_in[5], d_in[6], d_in[7], d_in[8],
        cbf, qbf, awf, abf, krw, krh, flag);
    wshufC_kernel<<<216, 256, 0, stream>>>(d_in[1], wsh, flag);
    wshufQ_kernel<<<24,  256, 0, stream>>>(d_in[3], wshQ, flag);

    qkv_mfma_kernel <<<dim3(2, 256), 256, 0, stream>>>(d_in[0], wshQ, qbf, flag, kbuf, qbuf, vbuf);
    conv_mfma_kernel<<<dim3(2, 256), 256, 0, stream>>>(d_in[0], wsh, cbf, flag, d_out);
    attn_mfma_kernel<<<dim3(16, 64), 256, 0, stream>>>(kbuf, qbuf, vbuf, krw, krh, atb);
    proj_kernel     <<<2048,         256, 0, stream>>>(atb, awf, abf, flag, d_out);
}

// Round 12
// 173.483 us; speedup vs baseline: 2.6567x; 1.0613x over previous
//
#include <hip/hip_runtime.h>
#include <cstdint>

using u16 = unsigned short;
using u32 = uint32_t;

typedef __attribute__((ext_vector_type(8))) short bf16x8;   // 8 bf16 = 4 VGPRs
typedef __attribute__((ext_vector_type(4))) float f32x4;    // MFMA accumulator

__device__ __forceinline__ float bf2f(u16 v) { return __uint_as_float(((u32)v) << 16); }
__device__ __forceinline__ u16 f2bf(float f) {
    u32 u = __float_as_uint(f);
    u += 0x7fffu + ((u >> 16) & 1u);   // RNE
    return (u16)(u >> 16);
}

// ---- workspace float offsets ----
#define FLAG_OFF 0
#define WSH_OFF  2097168   // conv weight bf16 fragments: u16[442368] = 221184 f
#define AWF_OFF  2588688   // 4096
#define CBF_OFF  2592784   // 192
#define QBF_OFF  2592976   // 192
#define ABF_OFF  2593168   // 64
#define KRW_OFF  2593232   // 504
#define KRH_OFF  2593736   // 504
#define KB_OFF   2594240   // kbuf bf16: u16[524288] (uses half the slot)
#define QB_OFF   3118528   // qbuf f32: 524288
#define VB_OFF   3642816   // vbuf bf16: u16[524288]
#define AT_OFF   4167104   // 524288
#define WSHQ_OFF 9409984   // qkv weight bf16 fragments: u16[49152] = 24576 f

// ---------------------------------------------------------------------------
// Dtype sniffer (verified; returns 0 on this problem's fp32 inputs).
// ---------------------------------------------------------------------------
__global__ void detect_kernel(const u16* __restrict__ x, int* __restrict__ flag) {
    __shared__ int cnt;
    if (threadIdx.x == 0) cnt = 0;
    __syncthreads();
    int c = 0;
    #pragma unroll
    for (int k = 0; k < 16; k++) {
        u16 v = x[threadIdx.x * 16 + k];
        int e = (v >> 7) & 0xFF;
        c += (e >= 110 && e <= 140) ? 1 : 0;
    }
    atomicAdd(&cnt, c);
    __syncthreads();
    if (threadIdx.x == 0) *flag = (cnt > 3300) ? 1 : 0;   // 1 = bf16 inputs
}

// ---------------------------------------------------------------------------
// Merged prep: wshufC (blocks 0..215), wshufQ (216..239), small cvt (240..261).
// Bodies identical to the R11-verified kernels.
// ---------------------------------------------------------------------------
__global__ __launch_bounds__(256) void prep_kernel(
    const void* __restrict__ cw, const void* __restrict__ qw,
    const void* __restrict__ cb, const void* __restrict__ qb,
    const void* __restrict__ aw, const void* __restrict__ ab,
    const void* __restrict__ kw_, const void* __restrict__ kh_,
    u16* __restrict__ wshC, u16* __restrict__ wshQ,
    float* __restrict__ cbf, float* __restrict__ qbf, float* __restrict__ awf,
    float* __restrict__ abf, float* __restrict__ krw, float* __restrict__ krh,
    const int* __restrict__ flag)
{
    const int blk = blockIdx.x;
    const int fl = *flag;
    if (blk < 240) {                         // weight shuffles into B-fragment order
        const void* w; u16* o; int g;
        if (blk < 216) { w = cw; o = wshC; g = blk * 256 + threadIdx.x; }
        else           { w = qw; o = wshQ; g = (blk - 216) * 256 + threadIdx.x; }
        const int kk = g / 768, rem = g % 768;
        const int tile = rem >> 6, lane = rem & 63;
        const int n = tile * 16 + (lane & 15);
        u16 tmp[8];
        #pragma unroll
        for (int j = 0; j < 8; j++) {
            const size_t k = (size_t)(kk * 32 + ((lane >> 4) << 3) + j);
            tmp[j] = fl ? ((const u16*)w)[k * 192 + n]
                        : f2bf(((const float*)w)[k * 192 + n]);
        }
        *(uint4*)(o + (size_t)g * 8) = *(const uint4*)tmp;
    } else {                                 // small-tensor fp32 normalize
        const int gid = (blk - 240) * 256 + threadIdx.x;
        const void* src; float* dst; int e;
        if      (gid <  192) { src = cb;  dst = cbf; e = gid; }
        else if (gid <  384) { src = qb;  dst = qbf; e = gid - 192; }
        else if (gid < 4480) { src = aw;  dst = awf; e = gid - 384; }
        else if (gid < 4544) { src = ab;  dst = abf; e = gid - 4480; }
        else if (gid < 5048) { src = kw_; dst = krw; e = gid - 4544; }
        else if (gid < 5552) { src = kh_; dst = krh; e = gid - 5048; }
        else return;
        dst[e] = fl ? bf2f(((const u16*)src)[e]) : ((const float*)src)[e];
    }
}

// ---------------------------------------------------------------------------
// QKV implicit GEMM, bf16 MFMA (R10/R11-verified body). Epilogue change:
// k and v are written as bf16 (identical numerics — attn f2bf'd them anyway);
// q stays f32 with scale 8^-0.5 * log2(e).
// ---------------------------------------------------------------------------
__global__ __launch_bounds__(256) void qkv_mfma_kernel(
    const void* __restrict__ xr, const u16* __restrict__ wsh, const float* __restrict__ qbf_,
    const int* __restrict__ flag,
    u16* __restrict__ kb16, float* __restrict__ qbuf, u16* __restrict__ vb16)
{
    const int coh = blockIdx.x, row = blockIdx.y;
    const int b = row >> 5, h = row & 31;
    const int t = threadIdx.x;
    __shared__ u16 xs[32 * 264];                            // 16896 B
    const int fl = *flag;

    if (fl) {
        const u16* src = (const u16*)xr + (size_t)row * 8192;
        #pragma unroll
        for (int i = 0; i < 4; ++i) {
            const int idx = t + i * 256;
            const int px = idx >> 5, cq = idx & 31;
            *(uint4*)(xs + px * 264 + cq * 8) = *(const uint4*)(src + px * 256 + cq * 8);
        }
    } else {
        const float* src = (const float*)xr + (size_t)row * 8192;
        #pragma unroll
        for (int i = 0; i < 8; ++i) {
            const int idx = t + i * 256;
            const int px = idx >> 6, c4 = idx & 63;
            float4 v = *(const float4*)(src + px * 256 + c4 * 4);
            u32 lo = (u32)f2bf(v.x) | ((u32)f2bf(v.y) << 16);
            u32 hi = (u32)f2bf(v.z) | ((u32)f2bf(v.w) << 16);
            *(uint2*)(xs + px * 264 + c4 * 4) = make_uint2(lo, hi);
        }
    }
    __syncthreads();

    const int lane = t & 63, wave = t >> 6;
    const int Mtile = wave & 1;
    const int tg0 = coh * 6 + (wave >> 1) * 3;
    const int l15 = lane & 15, quad = lane >> 4;

    f32x4 acc[3] = {{0,0,0,0},{0,0,0,0},{0,0,0,0}};

    const u16* ap = xs + (Mtile * 16 + l15) * 264 + quad * 8;
    #pragma unroll
    for (int kk = 0; kk < 8; ++kk) {
        const bf16x8 av = *(const bf16x8*)(ap + kk * 32);
        const u16* wp = wsh + ((size_t)(kk * 12 + tg0) * 64 + lane) * 8;
        const bf16x8 b0 = *(const bf16x8*)(wp);
        const bf16x8 b1 = *(const bf16x8*)(wp + 512);
        const bf16x8 b2 = *(const bf16x8*)(wp + 1024);
        acc[0] = __builtin_amdgcn_mfma_f32_16x16x32_bf16(av, b0, acc[0], 0, 0, 0);
        acc[1] = __builtin_amdgcn_mfma_f32_16x16x32_bf16(av, b1, acc[1], 0, 0, 0);
        acc[2] = __builtin_amdgcn_mfma_f32_16x16x32_bf16(av, b2, acc[2], 0, 0, 0);
    }

    // D layout (verified): col = lane&15, row = quad*4 + reg
    const int px0 = Mtile * 16 + quad * 4;
    #pragma unroll
    for (int ti = 0; ti < 3; ++ti) {
        const int tg = tg0 + ti;
        const int o = tg * 16 + l15;
        const int third = tg >> 2;                          // 0=k,1=q,2=v (wave-uniform)
        const int within = o - third * 64;
        const int n = within >> 3, d = within & 7;
        const float bias = qbf_[o];
        #pragma unroll
        for (int r = 0; r < 4; ++r) {
            const int i = h * 32 + px0 + r;
            const size_t off = ((size_t)(b * 8 + n) * 1024 + i) * 8 + d;
            const float val = acc[ti][r] + bias;
            if (third == 0)      kb16[off] = f2bf(val);
            else if (third == 1) qbuf[off] = val * 0.51006973050f;  // 8^-.5 * log2e
            else                 vb16[off] = f2bf(val);
        }
    }
}

// ---------------------------------------------------------------------------
// Conv 3x3 implicit GEMM, bf16 MFMA. VERIFIED — unchanged.
// ---------------------------------------------------------------------------
__global__ __launch_bounds__(256) void conv_mfma_kernel(
    const void* __restrict__ xr, const u16* __restrict__ wsh, const float* __restrict__ cbf,
    const int* __restrict__ flag, void* __restrict__ out)
{
    const int coh = blockIdx.x, row = blockIdx.y;
    const int b = row >> 5, h = row & 31;
    const int t = threadIdx.x;
    __shared__ u16 xs[3 * 34 * 264];                        // 53856 B
    const int fl = *flag;

    #pragma unroll
    for (int r = 0; r < 3; ++r) {
        const int hh = h + r - 1;
        if (t < 64) {
            const int s = (t >> 5) ? 33 : 0, cq = t & 31;
            *(uint4*)(xs + (r * 34 + s) * 264 + cq * 8) = make_uint4(0, 0, 0, 0);
        }
        const bool ok = (hh >= 0) && (hh < 32);
        const size_t base = ((size_t)((b * 32 + (ok ? hh : 0)) * 32)) * 256;
        if (fl) {
            const u16* src = (const u16*)xr + base;
            #pragma unroll
            for (int i = 0; i < 4; ++i) {
                const int idx = t + i * 256;
                const int px = idx >> 5, cq = idx & 31;
                uint4 v = ok ? *(const uint4*)(src + px * 256 + cq * 8)
                             : make_uint4(0, 0, 0, 0);
                *(uint4*)(xs + (r * 34 + 1 + px) * 264 + cq * 8) = v;
            }
        } else {
            const float* src = (const float*)xr + base;
            #pragma unroll
            for (int i = 0; i < 8; ++i) {
                const int idx = t + i * 256;
                const int px = idx >> 6, c4 = idx & 63;
                float4 v = ok ? *(const float4*)(src + px * 256 + c4 * 4)
                              : make_float4(0.f, 0.f, 0.f, 0.f);
                u32 lo = (u32)f2bf(v.x) | ((u32)f2bf(v.y) << 16);
                u32 hi = (u32)f2bf(v.z) | ((u32)f2bf(v.w) << 16);
                *(uint2*)(xs + (r * 34 + 1 + px) * 264 + c4 * 4) = make_uint2(lo, hi);
            }
        }
    }
    __syncthreads();

    const int lane = t & 63, wave = t >> 6;
    const int Mtile = wave & 1;
    const int tg0 = coh * 6 + (wave >> 1) * 3;
    const int l15 = lane & 15, quad = lane >> 4;

    f32x4 acc[3] = {{0,0,0,0},{0,0,0,0},{0,0,0,0}};

    #pragma unroll
    for (int p = 0; p < 9; ++p) {
        const int kh = p / 3, kw = p - kh * 3;
        const u16* ap = xs + (kh * 34 + kw + Mtile * 16 + l15) * 264 + quad * 8;
        #pragma unroll
        for (int ck = 0; ck < 8; ++ck) {
            const int kk = p * 8 + ck;
            const bf16x8 av = *(const bf16x8*)(ap + ck * 32);
            const u16* wp = wsh + ((size_t)(kk * 12 + tg0) * 64 + lane) * 8;
            const bf16x8 b0 = *(const bf16x8*)(wp);
            const bf16x8 b1 = *(const bf16x8*)(wp + 512);
            const bf16x8 b2 = *(const bf16x8*)(wp + 1024);
            acc[0] = __builtin_amdgcn_mfma_f32_16x16x32_bf16(av, b0, acc[0], 0, 0, 0);
            acc[1] = __builtin_amdgcn_mfma_f32_16x16x32_bf16(av, b1, acc[1], 0, 0, 0);
            acc[2] = __builtin_amdgcn_mfma_f32_16x16x32_bf16(av, b2, acc[2], 0, 0, 0);
        }
    }

    const int px0 = Mtile * 16 + quad * 4;
    #pragma unroll
    for (int ti = 0; ti < 3; ++ti) {
        const int co = (tg0 + ti) * 16 + l15;
        const float bias = cbf[co];
        #pragma unroll
        for (int r = 0; r < 4; ++r) {
            const size_t oidx = ((size_t)row * 32 + px0 + r) * 256 + co;
            const float v = acc[ti][r] + bias;
            if (fl) ((u16*)out)[oidx] = f2bf(v);
            else    ((float*)out)[oidx] = v;
        }
    }
}

// ---------------------------------------------------------------------------
// MFMA flash attention v2 (R11-verified machinery). Changes: K fragments load
// DIRECTLY from bf16 kbuf (address is quad-uniform -> HW broadcast, no LDS);
// V^T staged from bf16 vbuf (pure u16 moves); LDS 54.3 -> 37.5 KB = 4 blk/CU.
// ---------------------------------------------------------------------------
__global__ __launch_bounds__(256) void attn_mfma_kernel(
    const u16* __restrict__ kb16, const float* __restrict__ qbuf, const u16* __restrict__ vb16,
    const float* __restrict__ krw, const float* __restrict__ krh, float* __restrict__ attnbuf)
{
    const int qb = blockIdx.x;           // 0..15 (64 q-rows each)
    const int bn = blockIdx.y;           // 0..63
    const int b = bn >> 3, hn = bn & 7;
    const int t = threadIdx.x;
    const int i0 = qb * 64;

    __shared__ u16   sVT[8 * 1032];      // [d][key] bf16 (pad)    16512 B
    __shared__ u16   sRW[64 * 40];       // [ilocal][wk] bf16      5120 B
    __shared__ float sRH[32 * 68];       // [hk][ilocal] f32       8704 B
    __shared__ u16   sP [4 * 16 * 56];   // per-wave P, stride 56  7168 B  (37504 total)

    // ---- stage V^T from bf16 vbuf (no conversion) ----
    const u16* vg = vb16 + (size_t)bn * 8192;
    #pragma unroll
    for (int k4 = 0; k4 < 4; k4++) {
        const int key = t + k4 * 256;                 // 0..1023
        uint4 vv = *(const uint4*)(vg + key * 8);
        sVT[0 * 1032 + key] = (u16)(vv.x);  sVT[1 * 1032 + key] = (u16)(vv.x >> 16);
        sVT[2 * 1032 + key] = (u16)(vv.y);  sVT[3 * 1032 + key] = (u16)(vv.y >> 16);
        sVT[4 * 1032 + key] = (u16)(vv.z);  sVT[5 * 1032 + key] = (u16)(vv.z >> 16);
        sVT[6 * 1032 + key] = (u16)(vv.w);  sVT[7 * 1032 + key] = (u16)(vv.w >> 16);
    }
    // ---- rel tables: rw (bf16) and rh (f32 C-init) — R11-verified ----
    #pragma unroll
    for (int k8 = 0; k8 < 8; k8++) {
        const int idx = t + k8 * 256;                 // 0..2047
        const int il = idx >> 5, w = idx & 31;
        const int i = i0 + il;
        const float* q = qbuf + ((size_t)bn * 1024 + i) * 8;
        float4 qa = *(const float4*)q, qc = *(const float4*)(q + 4);
        const float* rp = krw + (size_t)(w - (i & 31) + 31) * 8;
        float4 ra = *(const float4*)rp, rc = *(const float4*)(rp + 4);
        sRW[il * 40 + w] = f2bf(qa.x*ra.x + qa.y*ra.y + qa.z*ra.z + qa.w*ra.w
                              + qc.x*rc.x + qc.y*rc.y + qc.z*rc.z + qc.w*rc.w);
        const float* hp = krh + (size_t)(w - (i >> 5) + 31) * 8;
        float4 ha = *(const float4*)hp, hc = *(const float4*)(hp + 4);
        sRH[w * 68 + il] = qa.x*ha.x + qa.y*ha.y + qa.z*ha.z + qa.w*ha.w
                         + qc.x*hc.x + qc.y*hc.y + qc.z*hc.z + qc.w*hc.w;
    }
    __syncthreads();

    const int lane = t & 63, wave = t >> 6;
    const int l15 = lane & 15, quad = lane >> 4;

    union Frag { u16 a[8]; bf16x8 v; };
    Frag Aq;
    {
        const float* q = qbuf + ((size_t)bn * 1024 + i0 + wave * 16 + l15) * 8;
        float4 qa = *(const float4*)q, qc = *(const float4*)(q + 4);
        Aq.a[0] = f2bf(qa.x); Aq.a[1] = f2bf(qa.y); Aq.a[2] = f2bf(qa.z); Aq.a[3] = f2bf(qa.w);
        Aq.a[4] = f2bf(qc.x); Aq.a[5] = f2bf(qc.y); Aq.a[6] = f2bf(qc.z); Aq.a[7] = f2bf(qc.w);
        if (quad != 0) {
            #pragma unroll
            for (int j = 0; j < 8; j++) Aq.a[j] = 0;
        }
    }
    const bf16x8 Arw = *(const bf16x8*)(sRW + (wave * 16 + l15) * 40 + quad * 8);

    Frag P0, P1, ONE;
    #pragma unroll
    for (int j = 0; j < 8; j++) { P0.a[j] = 0; P1.a[j] = 0; ONE.a[j] = 0x3F80; }
    {
        const int h0 = l15 - quad * 8;
        if (h0 >= 0 && h0 < 8) P0.a[h0] = 0x3F80;
        const int h1 = 16 + l15 - quad * 8;
        if (h1 >= 0 && h1 < 8) P1.a[h1] = 0x3F80;
    }

    const u16* kg = kb16 + (size_t)bn * 8192;
    u16* pb = sP + wave * (16 * 56);
    f32x4 oacc = {0.f, 0.f, 0.f, 0.f};

    for (int chunk = 0; chunk < 32; chunk++) {
        const float4 rh4 = *(const float4*)(sRH + chunk * 68 + wave * 16 + quad * 4);
        f32x4 acc0 = {rh4.x, rh4.y, rh4.z, rh4.w};
        f32x4 acc1 = acc0;
        // K fragments direct from global bf16 (quad-uniform address -> broadcast)
        const bf16x8 bk0 = *(const bf16x8*)(kg + (chunk * 32 + l15) * 8);
        const bf16x8 bk1 = *(const bf16x8*)(kg + (chunk * 32 + 16 + l15) * 8);
        acc0 = __builtin_amdgcn_mfma_f32_16x16x32_bf16(Aq.v, bk0, acc0, 0, 0, 0);
        acc0 = __builtin_amdgcn_mfma_f32_16x16x32_bf16(Arw, P0.v, acc0, 0, 0, 0);
        acc1 = __builtin_amdgcn_mfma_f32_16x16x32_bf16(Aq.v, bk1, acc1, 0, 0, 0);
        acc1 = __builtin_amdgcn_mfma_f32_16x16x32_bf16(Arw, P1.v, acc1, 0, 0, 0);
        #pragma unroll
        for (int r = 0; r < 4; r++) {
            const float p0 = exp2f(fminf(acc0[r], 80.0f));
            const float p1 = exp2f(fminf(acc1[r], 80.0f));
            pb[(quad * 4 + r) * 56 + l15]      = f2bf(p0);
            pb[(quad * 4 + r) * 56 + 16 + l15] = f2bf(p1);
        }
        const bf16x8 Ap = *(const bf16x8*)(pb + l15 * 56 + quad * 8);
        bf16x8 Bv;
        if (l15 < 8) Bv = *(const bf16x8*)(sVT + l15 * 1032 + chunk * 32 + quad * 8);
        else         Bv = ONE.v;   // n==8 -> l column
        oacc = __builtin_amdgcn_mfma_f32_16x16x32_bf16(Ap, Bv, oacc, 0, 0, 0);
    }

    #pragma unroll
    for (int r = 0; r < 4; r++) {
        const float lr = __shfl(oacc[r], (lane & 48) | 8, 64);
        const float val = oacc[r] / fmaxf(lr, 1e-30f);
        if (l15 < 8) {
            const int i = i0 + wave * 16 + quad * 4 + r;
            attnbuf[((size_t)b * 1024 + i) * 64 + hn * 8 + l15] = val;
        }
    }
}

// ---------------------------------------------------------------------------
// Output projection (VERIFIED — unchanged).
// ---------------------------------------------------------------------------
__global__ __launch_bounds__(256) void proj_kernel(
    const float* __restrict__ attnbuf, const float* __restrict__ awf, const float* __restrict__ abf,
    const int* __restrict__ flag, void* __restrict__ out)
{
    const int g = blockIdx.x * 256 + threadIdx.x;
    const int px = g >> 6, o = g & 63;
    const float* ar = attnbuf + (size_t)px * 64;
    float acc = abf[o];
    #pragma unroll 8
    for (int c = 0; c < 64; c++) acc += ar[c] * awf[c * 64 + o];
    if (*flag) ((u16*)out)[(size_t)px * 256 + 192 + o] = f2bf(acc);
    else       ((float*)out)[(size_t)px * 256 + 192 + o] = acc;
}

// ---------------------------------------------------------------------------
extern "C" void kernel_launch(void* const* d_in, const int* in_sizes, int n_in,
                              void* d_out, int out_size, void* d_ws, size_t ws_size,
                              hipStream_t stream)
{
    float* ws = (float*)d_ws;
    int*   flag = (int*)(ws + FLAG_OFF);
    u16*   wsh  = (u16*)(ws + WSH_OFF);
    float* awf  = ws + AWF_OFF;
    float* cbf  = ws + CBF_OFF;
    float* qbf  = ws + QBF_OFF;
    float* abf  = ws + ABF_OFF;
    float* krw  = ws + KRW_OFF;
    float* krh  = ws + KRH_OFF;
    u16*   kb16 = (u16*)(ws + KB_OFF);
    float* qbuf = ws + QB_OFF;
    u16*   vb16 = (u16*)(ws + VB_OFF);
    float* atb  = ws + AT_OFF;
    u16*   wshQ = (u16*)(ws + WSHQ_OFF);

    detect_kernel<<<1, 256, 0, stream>>>((const u16*)d_in[0], flag);

    prep_kernel<<<262, 256, 0, stream>>>(
        d_in[1], d_in[3], d_in[2], d_in[4], d_in[5], d_in[6], d_in[7], d_in[8],
        wsh, wshQ, cbf, qbf, awf, abf, krw, krh, flag);

    qkv_mfma_kernel <<<dim3(2, 256), 256, 0, stream>>>(d_in[0], wshQ, qbf, flag, kb16, qbuf, vb16);
    conv_mfma_kernel<<<dim3(2, 256), 256, 0, stream>>>(d_in[0], wsh, cbf, flag, d_out);
    attn_mfma_kernel<<<dim3(16, 64), 256, 0, stream>>>(kb16, qbuf, vb16, krw, krh, atb);
    proj_kernel     <<<2048,         256, 0, stream>>>(atb, awf, abf, flag, d_out);
}